// Round 4
// baseline (391.859 us; speedup 1.0000x reference)
//
#include <hip/hip_runtime.h>

typedef unsigned short u16;
typedef unsigned int u32;
typedef __attribute__((ext_vector_type(8))) short short8v;
typedef __attribute__((ext_vector_type(4))) short short4v;
typedef __attribute__((ext_vector_type(4))) float floatx4;

#define BB 4
#define SS 2048
#define DD 1024
#define HH 16
#define DKK 64
#define MM (BB * SS)   // 8192
#define KK DD
#define NN DD
// log2(e)/sqrt(DK): folded into Q projection so scores feed exp2 directly
#define QSCALE 0.18033688011112042f

__device__ __forceinline__ u16 f2bf(float f) {
  union { __bf16 h; u16 u; } r; r.h = (__bf16)f; return r.u;
}
__device__ __forceinline__ u32 pack2bf(float a, float b) {
  union { u32 u; __bf16 h[2]; } r;
  r.h[0] = (__bf16)a; r.h[1] = (__bf16)b; return r.u;
}
__device__ __forceinline__ short8v cat44(short4v a, short4v b) {
  return __builtin_shufflevector(a, b, 0, 1, 2, 3, 4, 5, 6, 7);
}

__device__ __forceinline__ void load_lds16(const void* g, void* l) {
  __builtin_amdgcn_global_load_lds((const __attribute__((address_space(1))) void*)g,
                                   (__attribute__((address_space(3))) void*)l, 16, 0, 0);
}

__device__ __forceinline__ floatx4 mfma_k32(short8v a, short8v b, floatx4 c) {
  return __builtin_amdgcn_mfma_f32_16x16x32_bf16(a, b, c, 0, 0, 0);
}

// ---------------- fp32 -> bf16 converts (fused launches) ----------------
__global__ __launch_bounds__(256) void cvt_w4(const float* __restrict__ w0,
                                              const float* __restrict__ w1,
                                              const float* __restrict__ w2,
                                              const float* __restrict__ w3,
                                              u16* __restrict__ out) {
  const int y = blockIdx.y;
  const float* in = (y == 0) ? w0 : (y == 1) ? w1 : (y == 2) ? w2 : w3;
  u16* o = out + (size_t)y * DD * DD;
  const int i = (blockIdx.x * 256 + threadIdx.x) * 8;
  float4 a = *(const float4*)(in + i);
  float4 b = *(const float4*)(in + i + 4);
  uint4 v;
  v.x = pack2bf(a.x, a.y); v.y = pack2bf(a.z, a.w);
  v.z = pack2bf(b.x, b.y); v.w = pack2bf(b.z, b.w);
  *(uint4*)(o + i) = v;
}

__global__ __launch_bounds__(256) void cvt_a3(const float* __restrict__ a0,
                                              const float* __restrict__ a1,
                                              const float* __restrict__ a2,
                                              u16* __restrict__ o0, u16* __restrict__ o1,
                                              u16* __restrict__ o2) {
  const int y = blockIdx.y;
  const float* in = (y == 0) ? a0 : (y == 1) ? a1 : a2;
  u16* o = (y == 0) ? o0 : (y == 1) ? o1 : o2;
  const int i = (blockIdx.x * 256 + threadIdx.x) * 8;
  float4 a = *(const float4*)(in + i);
  float4 b = *(const float4*)(in + i + 4);
  uint4 v;
  v.x = pack2bf(a.x, a.y); v.y = pack2bf(a.z, a.w);
  v.z = pack2bf(b.x, b.y); v.w = pack2bf(b.z, b.w);
  *(uint4*)(o + i) = v;
}

// ================= 256x256 8-phase GEMM core (T2+T3+T4+T5) =================
// BM=BN=256, BK=64, 2 K-tiles/iteration, 8 waves (2M x 4N), per-wave 128x64.
// LDS: As/Bs each [2 dbuf][2 half][128 rows][64 k] bf16 = 64 KiB -> 128 KiB total.
// Swizzle (T2): element (r,c) stored at c' = c ^ ((r&7)<<3). 16B-group-granular,
// so global_load_lds keeps a LINEAR LDS dest and the SOURCE 16B-group is
// pre-swizzled per lane (rule #21). ds_read of a frag column then spreads the
// 16 rows across 8 distinct 16B slots -> 2-way bank aliasing (free).
// Schedule (ledger-derived; counted waits, never drain-0 in steady state):
//   iter j consumes tile e=2j (dbuf0, phases 0-3) and o=2j+1 (dbuf1, phases 4-7).
//   stages: p0:A0(o) p1:A1(o) p2:B0(e+2) p3:B1(e+2) p4:A0(e+2) p5:A1(e+2)
//           p6:B0(o+2) p7:B1(o+2)   (each 2 x global_load_lds per thread)
//   waits: vmcnt(4) at p3 and p7 (2 half-tiles in flight). Last iter p3: vmcnt(0).
#define NT (KK / 64)     // 16 K-tiles
#define ITERS (NT / 2)   // 8

__device__ __forceinline__ void stage_half(const u16* __restrict__ gsrc, u16* ldst,
                                           int tid) {
#pragma unroll
  for (int L = 0; L < 2; ++L) {
    const int s = L * 512 + tid;
    const int r = s >> 3;
    const int g = (s & 7) ^ (r & 7);   // inverse-swizzled source 16B-group
    load_lds16(gsrc + (size_t)r * KK + g * 8, ldst + s * 8);
  }
}

__device__ __forceinline__ void gemm256_core(const u16* __restrict__ A,  // + m0*KK
                                             const u16* __restrict__ W,  // + n0*KK
                                             u16* As, u16* Bs,           // [2][2][8192]
                                             floatx4 (&acc)[8][4]) {
  const int tid = threadIdx.x;
  const int w = tid >> 6, lane = tid & 63;
  const int wm = w >> 2, wn = w & 3;
  const int wnh = wn >> 1, wno = wn & 1;
  const int lr = lane & 15;
  // swizzled col base for kk=0; kk=1 flips bit5 (c0 ^ 32)
  const int c0 = (((lane >> 2) & 1) << 5) | ((((lane >> 4) ^ lane) & 3) << 3);

#define AP(d, fr, kk) \
  (*(const short8v*)(As + ((d)*2 + wm) * 8192 + ((fr)*16 + lr) * 64 + (c0 ^ ((kk)*32))))
#define BP(d, fc, kk) \
  (*(const short8v*)(Bs + ((d)*2 + wnh) * 8192 + (wno * 64 + (fc)*16 + lr) * 64 + (c0 ^ ((kk)*32))))
#define MFMA8(FROFF, B, FCOFF)                                                  \
  _Pragma("unroll") for (int fr_ = 0; fr_ < 4; ++fr_)                           \
  _Pragma("unroll") for (int fc_ = 0; fc_ < 2; ++fc_) {                         \
    acc[(FROFF) + fr_][(FCOFF) + fc_] =                                         \
        mfma_k32(a[fr_][0], B[fc_][0], acc[(FROFF) + fr_][(FCOFF) + fc_]);      \
    acc[(FROFF) + fr_][(FCOFF) + fc_] =                                         \
        mfma_k32(a[fr_][1], B[fc_][1], acc[(FROFF) + fr_][(FCOFF) + fc_]);      \
  }
#define BAR() __builtin_amdgcn_s_barrier()
#define PRIO1() __builtin_amdgcn_s_setprio(1)
#define PRIO0() __builtin_amdgcn_s_setprio(0)

  short8v a[4][2], b01[2][2], b23[2][2];

  // prologue: tile0 all 4 halves + tile1 B-halves; wait first 4 halves landed
  stage_half(A, As + 0 * 8192, tid);
  stage_half(A + (size_t)128 * KK, As + 1 * 8192, tid);
  stage_half(W, Bs + 0 * 8192, tid);
  stage_half(W + (size_t)128 * KK, Bs + 1 * 8192, tid);
  stage_half(W + 64, Bs + 2 * 8192, tid);
  stage_half(W + (size_t)128 * KK + 64, Bs + 3 * 8192, tid);
  asm volatile("s_waitcnt vmcnt(4)" ::: "memory");
  BAR();

#pragma unroll 1
  for (int j = 0; j < ITERS; ++j) {
    const int e = 2 * j, o = e + 1;
    const bool haveE2 = (j + 1 < ITERS);
    // ---- phase 0: tile e reads A fr0-3 + B fc0-1; stage A0(o) -> d1 H0
#pragma unroll
    for (int fr = 0; fr < 4; ++fr) { a[fr][0] = AP(0, fr, 0); a[fr][1] = AP(0, fr, 1); }
#pragma unroll
    for (int fc = 0; fc < 2; ++fc) { b01[fc][0] = BP(0, fc, 0); b01[fc][1] = BP(0, fc, 1); }
    stage_half(A + (size_t)o * 64, As + 2 * 8192, tid);
    BAR(); PRIO1(); MFMA8(0, b01, 0); PRIO0(); BAR();
    // ---- phase 1: reads B fc2-3; stage A1(o) -> d1 H1
#pragma unroll
    for (int fc = 0; fc < 2; ++fc) { b23[fc][0] = BP(0, fc + 2, 0); b23[fc][1] = BP(0, fc + 2, 1); }
    stage_half(A + (size_t)128 * KK + (size_t)o * 64, As + 3 * 8192, tid);
    BAR(); PRIO1(); MFMA8(0, b23, 2); PRIO0(); BAR();
    // ---- phase 2: reads A fr4-7; stage B0(e+2) -> d0 H0
#pragma unroll
    for (int fr = 0; fr < 4; ++fr) { a[fr][0] = AP(0, fr + 4, 0); a[fr][1] = AP(0, fr + 4, 1); }
    if (haveE2) stage_half(W + (size_t)(e + 2) * 64, Bs + 0 * 8192, tid);
    BAR(); PRIO1(); MFMA8(4, b01, 0); PRIO0(); BAR();
    // ---- phase 3: stage B1(e+2) -> d0 H1; counted wait
    if (haveE2) {
      stage_half(W + (size_t)128 * KK + (size_t)(e + 2) * 64, Bs + 1 * 8192, tid);
      asm volatile("s_waitcnt vmcnt(4)" ::: "memory");
    } else {
      asm volatile("s_waitcnt vmcnt(0)" ::: "memory");
    }
    BAR(); PRIO1(); MFMA8(4, b23, 2); PRIO0(); BAR();
    // ---- phase 4: tile o reads A fr0-3 + B fc0-1 (d1); stage A0(e+2) -> d0 H0
#pragma unroll
    for (int fr = 0; fr < 4; ++fr) { a[fr][0] = AP(1, fr, 0); a[fr][1] = AP(1, fr, 1); }
#pragma unroll
    for (int fc = 0; fc < 2; ++fc) { b01[fc][0] = BP(1, fc, 0); b01[fc][1] = BP(1, fc, 1); }
    if (haveE2) stage_half(A + (size_t)(e + 2) * 64, As + 0 * 8192, tid);
    BAR(); PRIO1(); MFMA8(0, b01, 0); PRIO0(); BAR();
    // ---- phase 5: reads B fc2-3 (d1); stage A1(e+2) -> d0 H1
#pragma unroll
    for (int fc = 0; fc < 2; ++fc) { b23[fc][0] = BP(1, fc + 2, 0); b23[fc][1] = BP(1, fc + 2, 1); }
    if (haveE2) stage_half(A + (size_t)128 * KK + (size_t)(e + 2) * 64, As + 1 * 8192, tid);
    BAR(); PRIO1(); MFMA8(0, b23, 2); PRIO0(); BAR();
    // ---- phase 6: reads A fr4-7 (d1); stage B0(o+2) -> d1 H0
#pragma unroll
    for (int fr = 0; fr < 4; ++fr) { a[fr][0] = AP(1, fr + 4, 0); a[fr][1] = AP(1, fr + 4, 1); }
    if (haveE2) stage_half(W + (size_t)(o + 2) * 64, Bs + 2 * 8192, tid);
    BAR(); PRIO1(); MFMA8(4, b01, 0); PRIO0(); BAR();
    // ---- phase 7: stage B1(o+2) -> d1 H1; counted wait (skip entirely on last)
    if (haveE2) {
      stage_half(W + (size_t)128 * KK + (size_t)(o + 2) * 64, Bs + 3 * 8192, tid);
      asm volatile("s_waitcnt vmcnt(4)" ::: "memory");
    }
    BAR(); PRIO1(); MFMA8(4, b23, 2); PRIO0(); BAR();
  }
#undef AP
#undef BP
#undef MFMA8
#undef BAR
#undef PRIO1
#undef PRIO0
}

// ---------------- fused QKV projection (blockIdx.z selects q/k/v) ----------------
__global__ __launch_bounds__(512, 2) void proj_gemm(
    const u16* __restrict__ qc, const u16* __restrict__ kc, const u16* __restrict__ vc,
    const u16* __restrict__ Wq, const u16* __restrict__ Wk, const u16* __restrict__ Wv,
    const float* __restrict__ bq, const float* __restrict__ bk, const float* __restrict__ bv,
    u16* __restrict__ Qb, u16* __restrict__ Kb, u16* __restrict__ Vtb) {
  __shared__ __align__(16) u16 As[2 * 2 * 8192];
  __shared__ __align__(16) u16 Bs[2 * 2 * 8192];
  const int z = blockIdx.z;
  const u16* A = (z == 0) ? qc : (z == 1) ? kc : vc;
  const u16* W = (z == 0) ? Wq : (z == 1) ? Wk : Wv;
  const float* bias = (z == 0) ? bq : (z == 1) ? bk : bv;
  const int m0 = blockIdx.x * 256, n0 = blockIdx.y * 256;

  floatx4 acc[8][4] = {};
  gemm256_core(A + (size_t)m0 * KK, W + (size_t)n0 * KK, As, Bs, acc);

  const int tid = threadIdx.x;
  const int w = tid >> 6, lane = tid & 63;
  const int lr = lane & 15, lq = lane >> 4;
  const int wm = w >> 2, wn = w & 3;
  const int row0 = m0 + wm * 128;
  const int col0 = n0 + wn * 64;

  if (z == 2) {
    // V^T store [B,H,DK,S]: rr=0..3 are consecutive s -> packed b64
#pragma unroll
    for (int fc = 0; fc < 4; ++fc) {
      const int col = col0 + fc * 16 + lr;
      const float bv_ = bias[col];
      const int h = col >> 6, dk = col & 63;
#pragma unroll
      for (int fr = 0; fr < 8; ++fr) {
        const int row = row0 + fr * 16 + lq * 4;
        const int b = row >> 11, s = row & (SS - 1);
        uint2 pk;
        pk.x = pack2bf(acc[fr][fc][0] + bv_, acc[fr][fc][1] + bv_);
        pk.y = pack2bf(acc[fr][fc][2] + bv_, acc[fr][fc][3] + bv_);
        *(uint2*)&Vtb[(((size_t)(b * HH + h)) * DKK + dk) * SS + s] = pk;
      }
    }
  } else {
    u16* out = (z == 0) ? Qb : Kb;
    const float sc = (z == 0) ? QSCALE : 1.0f;
#pragma unroll
    for (int fc = 0; fc < 4; ++fc) {
      const int col = col0 + fc * 16 + lr;
      const float bv_ = bias[col];
#pragma unroll
      for (int fr = 0; fr < 8; ++fr)
#pragma unroll
        for (int rr = 0; rr < 4; ++rr) {
          const int row = row0 + fr * 16 + lq * 4 + rr;
          out[(size_t)row * NN + col] = f2bf((acc[fr][fc][rr] + bv_) * sc);
        }
    }
  }
}

// ---------------- output GEMM (fp32 store) ----------------
__global__ __launch_bounds__(512, 2) void out_gemm(const u16* __restrict__ A,
                                                   const u16* __restrict__ W,
                                                   const float* __restrict__ bias,
                                                   float* __restrict__ out) {
  __shared__ __align__(16) u16 As[2 * 2 * 8192];
  __shared__ __align__(16) u16 Bs[2 * 2 * 8192];
  const int m0 = blockIdx.x * 256, n0 = blockIdx.y * 256;
  floatx4 acc[8][4] = {};
  gemm256_core(A + (size_t)m0 * KK, W + (size_t)n0 * KK, As, Bs, acc);

  const int tid = threadIdx.x;
  const int w = tid >> 6, lane = tid & 63;
  const int lr = lane & 15, lq = lane >> 4;
  const int wm = w >> 2, wn = w & 3;
  const int row0 = m0 + wm * 128;
  const int col0 = n0 + wn * 64;
#pragma unroll
  for (int fc = 0; fc < 4; ++fc) {
    const int col = col0 + fc * 16 + lr;
    const float bv = bias[col];
#pragma unroll
    for (int fr = 0; fr < 8; ++fr)
#pragma unroll
      for (int rr = 0; rr < 4; ++rr) {
        const int row = row0 + fr * 16 + lq * 4 + rr;
        out[(size_t)row * NN + col] = acc[fr][fc][rr] + bv;
      }
  }
}

// ---------------- flash attention r7: swapped-QK, register-resident P ----------------
// QK computed SWAPPED: sc_T = mfma(A=K-frag, B=Q-frag) -> D[key][q].
//   Q's A-frag and B-frag per-lane layouts are identical (m/n=lane&15, k=8lq+j),
//   so loads are unchanged. Lane (lq,lr) holds P[key=16t+4lq+r][q=lr].
// PV uses contraction permutation pi(k) = 16*((k&7)>>2) + 4*(k>>3) + (k&3) on BOTH
//   operands: A-side P frag becomes LANE-LOCAL: pa[H] slot j = sc_T[2H+(j>>2)][j&3]
//   (pure cvt_pk packing, no LDS round-trip); B-side V frag absorbs pi via two
//   ds_read_b64 per frag from the UNCHANGED Vs staging layout at
//   addr16 = 1024*t + 512*H + 128*(2b+(lq>>1)) + 8*lr + 4*(lq&1)   (b = j>>2).
//   Bank audit: word = (4lr + 2(lq&1) + c) mod 32 -> exactly 4 words/bank (b64
//   floor) = conflict-free. Output D-layout of PV is unchanged (rows q=4lq+r,
//   cols dk=16t+lr) so the epilogue store is identical; only the softmax denom
//   moves: per-lane scalar over its 16 keys (q=lr), reduced once at the end via
//   shfl_xor(16,32) then redistributed to q=4lq+r rows by 8 shfls.
// Ps LDS freed -> Vs double-buffers too (LDS 32768 B, 5 blocks/CU) and the loop
// drops to 2 barriers + 1 counted wait per iter (ledger):
//   iter kt: B0 (closes QK/PV(kt-1) reads of buf bf^1)
//            issue K(kt+1)->Ks[bf^1] [2], V(kt+1)->Vs[bf^1] [2]
//            vmcnt(4) -> K(kt),V(kt) landed   [last iter: vmcnt(0)]
//            B1; QK -> softmax/pack -> PV, all barrier-free.
__global__ __launch_bounds__(256, 5) void attn_kernel(const u16* __restrict__ Q,
                                                      const u16* __restrict__ Kmat,
                                                      const u16* __restrict__ Vt,
                                                      u16* __restrict__ ctx) {
  __shared__ __align__(16) u16 Ks[2][64 * 64];  // chunk 2t+half: key 16t+lr, dk 32*half+8lq+j
  __shared__ __align__(16) u16 Vs[2][64 * 64];  // chunk 2t+half: dk 16t+lr, key 32*half+8lq+j
  const int tid = threadIdx.x;
  const int w = tid >> 6, lane = tid & 63;
  const int lr = lane & 15, lq = lane >> 4;
  const int bh = blockIdx.x, b = bh >> 4, h = bh & 15;
  const int q0 = blockIdx.y * 128;

  // Q fragment (dual-use A/B layout): lane holds Q[q=lr(+strip)][dk=8lq+j (+32)]
  short8v qf[2][2];
  {
    const u16* qp = Q + ((size_t)(b * SS + q0 + w * 32 + lr)) * DD + h * 64 + lq * 8;
    qf[0][0] = *(const short8v*)qp;
    qf[0][1] = *(const short8v*)(qp + 32);
    qf[1][0] = *(const short8v*)(qp + 16 * DD);
    qf[1][1] = *(const short8v*)(qp + 16 * DD + 32);
  }
  floatx4 o[2][4] = {};   // o[s][t]: row q=4lq+r, col dk=16t+lr (unchanged layout)
  float l_part[2] = {};   // per-lane partial denom for q=lr, keys {16t+4lq+r} per iter

  const u16* kp = Kmat + ((size_t)(b * SS + w * 16 + lr)) * DD + h * 64 + lq * 8;
  const u16* vp = Vt + (((size_t)(b * HH + h)) * DKK + w * 16 + lr) * SS + lq * 8;
  const int vbase = 128 * (lq >> 1) + 8 * lr + 4 * (lq & 1);  // u16 units

  // prologue: stage K(0),V(0) -> buf 0
  load_lds16(kp,      &Ks[0][(2 * w) * 512]);
  load_lds16(kp + 32, &Ks[0][(2 * w + 1) * 512]);
  load_lds16(vp,      &Vs[0][(2 * w) * 512]);
  load_lds16(vp + 32, &Vs[0][(2 * w + 1) * 512]);
  kp += 64 * DD; vp += 64;

#pragma unroll 1
  for (int kt = 0; kt < SS / 64; ++kt) {
    const int bf = kt & 1;
    const bool haveNext = (kt + 1 < SS / 64);
    __builtin_amdgcn_s_barrier();  // B0: closes QK/PV(kt-1) reads of buf bf^1
    if (haveNext) {
      load_lds16(kp,      &Ks[bf ^ 1][(2 * w) * 512]);
      load_lds16(kp + 32, &Ks[bf ^ 1][(2 * w + 1) * 512]);
      load_lds16(vp,      &Vs[bf ^ 1][(2 * w) * 512]);
      load_lds16(vp + 32, &Vs[bf ^ 1][(2 * w + 1) * 512]);
      kp += 64 * DD; vp += 64;
      // W1: outstanding <= [K(kt) 2, V(kt) 2, K(kt+1) 2, V(kt+1) 2]
      //     vmcnt(4) -> K(kt),V(kt) landed
      asm volatile("s_waitcnt vmcnt(4)" ::: "memory");
    } else {
      asm volatile("s_waitcnt vmcnt(0)" ::: "memory");
    }
    __builtin_amdgcn_s_barrier();  // B1: K(kt),V(kt) landed in all waves

    // swapped QK: sc[s][t] = D[key=16t+4lq+r][q=lr] (A=K, B=Q; loads unchanged)
    floatx4 sc[2][4] = {};
    __builtin_amdgcn_s_setprio(1);
#pragma unroll
    for (int t = 0; t < 4; ++t) {
      short8v kb0 = *(const short8v*)&Ks[bf][t * 1024 + lane * 8];
      short8v kb1 = *(const short8v*)&Ks[bf][t * 1024 + 512 + lane * 8];
#pragma unroll
      for (int s = 0; s < 2; ++s) {
        sc[s][t] = mfma_k32(kb0, qf[s][0], sc[s][t]);
        sc[s][t] = mfma_k32(kb1, qf[s][1], sc[s][t]);
      }
    }
    __builtin_amdgcn_s_setprio(0);

    // softmax + in-register P pack: pa[s][H] slot j = sc[s][2H+(j>>2)][j&3]
    short8v pa[2][2];
#pragma unroll
    for (int s = 0; s < 2; ++s) {
      float lp = 0.0f;
#pragma unroll
      for (int t = 0; t < 4; ++t)
#pragma unroll
        for (int r = 0; r < 4; ++r) {
          const float e = __builtin_amdgcn_exp2f(sc[s][t][r]);
          sc[s][t][r] = e;
          lp += e;
        }
      l_part[s] += lp;
#pragma unroll
      for (int H = 0; H < 2; ++H) {
        union { u32 u[4]; short8v v; } pb;
        pb.u[0] = pack2bf(sc[s][2 * H][0], sc[s][2 * H][1]);
        pb.u[1] = pack2bf(sc[s][2 * H][2], sc[s][2 * H][3]);
        pb.u[2] = pack2bf(sc[s][2 * H + 1][0], sc[s][2 * H + 1][1]);
        pb.u[3] = pack2bf(sc[s][2 * H + 1][2], sc[s][2 * H + 1][3]);
        pa[s][H] = pb.v;
      }
    }

    // PV with pi-permuted contraction; V read as 2x ds_read_b64 per frag
    const u16* vsb = &Vs[bf][0];
    __builtin_amdgcn_s_setprio(1);
#pragma unroll
    for (int t = 0; t < 4; ++t) {
      short8v vb0 = cat44(*(const short4v*)&vsb[t * 1024 + vbase],
                          *(const short4v*)&vsb[t * 1024 + vbase + 256]);
      short8v vb1 = cat44(*(const short4v*)&vsb[t * 1024 + 512 + vbase],
                          *(const short4v*)&vsb[t * 1024 + 512 + vbase + 256]);
#pragma unroll
      for (int s = 0; s < 2; ++s) {
        o[s][t] = mfma_k32(pa[s][0], vb0, o[s][t]);
        o[s][t] = mfma_k32(pa[s][1], vb1, o[s][t]);
      }
    }
    __builtin_amdgcn_s_setprio(0);
  }

  // denom: full sum for q=lr, then redistribute to q=4lq+r rows
  float inv[2][4];
#pragma unroll
  for (int s = 0; s < 2; ++s) {
    float l = l_part[s];
    l += __shfl_xor(l, 16);
    l += __shfl_xor(l, 32);
#pragma unroll
    for (int r = 0; r < 4; ++r)
      inv[s][r] = 1.0f / __shfl(l, lq * 4 + r);
  }

#pragma unroll
  for (int s = 0; s < 2; ++s)
#pragma unroll
    for (int r = 0; r < 4; ++r) {
      const int sq = q0 + w * 32 + s * 16 + lq * 4 + r;
      u16* cp = ctx + ((size_t)(b * SS + sq)) * DD + h * 64;
      const float iv = inv[s][r];
#pragma unroll
      for (int t = 0; t < 4; ++t)
        cp[t * 16 + lr] = f2bf(o[s][t][r] * iv);
    }
}

// ---------------- launch ----------------
extern "C" void kernel_launch(void* const* d_in, const int* in_sizes, int n_in,
                              void* d_out, int out_size, void* d_ws, size_t ws_size,
                              hipStream_t stream) {
  const float* query = (const float*)d_in[0];
  const float* key   = (const float*)d_in[1];
  const float* value = (const float*)d_in[2];
  const float* Wq = (const float*)d_in[3];  const float* bq = (const float*)d_in[4];
  const float* Wk = (const float*)d_in[5];  const float* bk = (const float*)d_in[6];
  const float* Wv = (const float*)d_in[7];  const float* bv = (const float*)d_in[8];
  const float* Wo = (const float*)d_in[9];  const float* bo = (const float*)d_in[10];
  float* out = (float*)d_out;

  char* ws = (char*)d_ws;
  size_t off = 0;
  u16* Wb   = (u16*)(ws + off); off += (size_t)4 * DD * DD * 2;  // Wq,Wk,Wv,Wo bf16
  u16* Qb   = (u16*)(ws + off); off += (size_t)MM * DD * 2;      // scaled Q [B,S,D]
  u16* Kb   = (u16*)(ws + off); off += (size_t)MM * DD * 2;      // [B,S,D]
  u16* Vtb  = (u16*)(ws + off); off += (size_t)MM * DD * 2;      // [B,H,DK,S]
  u16* qc   = (u16*)(ws + off);
  u16* ctxb = qc;               off += (size_t)MM * DD * 2;      // ctx aliases qc
  u16* kc = (u16*)d_out;                       // scratch in d_out (overwritten last)
  u16* vc = (u16*)d_out + (size_t)MM * DD;
  u16* Wq_b = Wb, *Wk_b = Wb + (size_t)DD * DD, *Wv_b = Wb + (size_t)2 * DD * DD,
     *Wo_b = Wb + (size_t)3 * DD * DD;

  const int wn = DD * DD, an = MM * DD;
  cvt_w4<<<dim3(wn / 2048, 4), 256, 0, stream>>>(Wq, Wk, Wv, Wo, Wb);
  cvt_a3<<<dim3(an / 2048, 3), 256, 0, stream>>>(query, key, value, qc, kc, vc);

  proj_gemm<<<dim3(MM / 256, NN / 256, 3), 512, 0, stream>>>(
      qc, kc, vc, Wq_b, Wk_b, Wv_b, bq, bk, bv, Qb, Kb, Vtb);

  attn_kernel<<<dim3(BB * HH, SS / 128), 256, 0, stream>>>(Qb, Kb, Vtb, ctxb);

  out_gemm<<<dim3(MM / 256, NN / 256), 512, 0, stream>>>(ctxb, Wo_b, bo, out);
}

// Round 5
// 345.319 us; speedup vs baseline: 1.1348x; 1.1348x over previous
//
#include <hip/hip_runtime.h>

typedef unsigned short u16;
typedef unsigned int u32;
typedef __attribute__((ext_vector_type(8))) short short8v;
typedef __attribute__((ext_vector_type(4))) float floatx4;

#define BB 4
#define SS 2048
#define DD 1024
#define HH 16
#define DKK 64
#define MM (BB * SS)   // 8192
#define KK DD
#define NN DD
// log2(e)/sqrt(DK): folded into Q projection so scores feed exp2 directly
#define QSCALE 0.18033688011112042f

__device__ __forceinline__ u16 f2bf(float f) {
  union { __bf16 h; u16 u; } r; r.h = (__bf16)f; return r.u;
}
__device__ __forceinline__ u32 pack2bf(float a, float b) {
  union { u32 u; __bf16 h[2]; } r;
  r.h[0] = (__bf16)a; r.h[1] = (__bf16)b; return r.u;
}

__device__ __forceinline__ void load_lds16(const void* g, void* l) {
  __builtin_amdgcn_global_load_lds((const __attribute__((address_space(1))) void*)g,
                                   (__attribute__((address_space(3))) void*)l, 16, 0, 0);
}

__device__ __forceinline__ floatx4 mfma_k32(short8v a, short8v b, floatx4 c) {
  return __builtin_amdgcn_mfma_f32_16x16x32_bf16(a, b, c, 0, 0, 0);
}

// ---------------- fp32 -> bf16 converts (fused launches) ----------------
__global__ __launch_bounds__(256) void cvt_w4(const float* __restrict__ w0,
                                              const float* __restrict__ w1,
                                              const float* __restrict__ w2,
                                              const float* __restrict__ w3,
                                              u16* __restrict__ out) {
  const int y = blockIdx.y;
  const float* in = (y == 0) ? w0 : (y == 1) ? w1 : (y == 2) ? w2 : w3;
  u16* o = out + (size_t)y * DD * DD;
  const int i = (blockIdx.x * 256 + threadIdx.x) * 8;
  float4 a = *(const float4*)(in + i);
  float4 b = *(const float4*)(in + i + 4);
  uint4 v;
  v.x = pack2bf(a.x, a.y); v.y = pack2bf(a.z, a.w);
  v.z = pack2bf(b.x, b.y); v.w = pack2bf(b.z, b.w);
  *(uint4*)(o + i) = v;
}

__global__ __launch_bounds__(256) void cvt_a3(const float* __restrict__ a0,
                                              const float* __restrict__ a1,
                                              const float* __restrict__ a2,
                                              u16* __restrict__ o0, u16* __restrict__ o1,
                                              u16* __restrict__ o2) {
  const int y = blockIdx.y;
  const float* in = (y == 0) ? a0 : (y == 1) ? a1 : a2;
  u16* o = (y == 0) ? o0 : (y == 1) ? o1 : o2;
  const int i = (blockIdx.x * 256 + threadIdx.x) * 8;
  float4 a = *(const float4*)(in + i);
  float4 b = *(const float4*)(in + i + 4);
  uint4 v;
  v.x = pack2bf(a.x, a.y); v.y = pack2bf(a.z, a.w);
  v.z = pack2bf(b.x, b.y); v.w = pack2bf(b.z, b.w);
  *(uint4*)(o + i) = v;
}

// ================= 256x256 8-phase GEMM core (T2+T3+T4+T5) =================
// BM=BN=256, BK=64, 2 K-tiles/iteration, 8 waves (2M x 4N), per-wave 128x64.
// LDS: As/Bs each [2 dbuf][2 half][128 rows][64 k] bf16 = 64 KiB -> 128 KiB total.
// Swizzle (T2): element (r,c) stored at c' = c ^ ((r&7)<<3). 16B-group-granular,
// so global_load_lds keeps a LINEAR LDS dest and the SOURCE 16B-group is
// pre-swizzled per lane (rule #21). ds_read of a frag column then spreads the
// 16 rows across 8 distinct 16B slots -> 2-way bank aliasing (free).
// Schedule (ledger-derived; counted waits, never drain-0 in steady state):
//   iter j consumes tile e=2j (dbuf0, phases 0-3) and o=2j+1 (dbuf1, phases 4-7).
//   stages: p0:A0(o) p1:A1(o) p2:B0(e+2) p3:B1(e+2) p4:A0(e+2) p5:A1(e+2)
//           p6:B0(o+2) p7:B1(o+2)   (each 2 x global_load_lds per thread)
//   waits: vmcnt(4) at p3 and p7 (2 half-tiles in flight). Last iter p3: vmcnt(0).
#define NT (KK / 64)     // 16 K-tiles
#define ITERS (NT / 2)   // 8

__device__ __forceinline__ void stage_half(const u16* __restrict__ gsrc, u16* ldst,
                                           int tid) {
#pragma unroll
  for (int L = 0; L < 2; ++L) {
    const int s = L * 512 + tid;
    const int r = s >> 3;
    const int g = (s & 7) ^ (r & 7);   // inverse-swizzled source 16B-group
    load_lds16(gsrc + (size_t)r * KK + g * 8, ldst + s * 8);
  }
}

__device__ __forceinline__ void gemm256_core(const u16* __restrict__ A,  // + m0*KK
                                             const u16* __restrict__ W,  // + n0*KK
                                             u16* As, u16* Bs,           // [2][2][8192]
                                             floatx4 (&acc)[8][4]) {
  const int tid = threadIdx.x;
  const int w = tid >> 6, lane = tid & 63;
  const int wm = w >> 2, wn = w & 3;
  const int wnh = wn >> 1, wno = wn & 1;
  const int lr = lane & 15;
  // swizzled col base for kk=0; kk=1 flips bit5 (c0 ^ 32)
  const int c0 = (((lane >> 2) & 1) << 5) | ((((lane >> 4) ^ lane) & 3) << 3);

#define AP(d, fr, kk) \
  (*(const short8v*)(As + ((d)*2 + wm) * 8192 + ((fr)*16 + lr) * 64 + (c0 ^ ((kk)*32))))
#define BP(d, fc, kk) \
  (*(const short8v*)(Bs + ((d)*2 + wnh) * 8192 + (wno * 64 + (fc)*16 + lr) * 64 + (c0 ^ ((kk)*32))))
#define MFMA8(FROFF, B, FCOFF)                                                  \
  _Pragma("unroll") for (int fr_ = 0; fr_ < 4; ++fr_)                           \
  _Pragma("unroll") for (int fc_ = 0; fc_ < 2; ++fc_) {                         \
    acc[(FROFF) + fr_][(FCOFF) + fc_] =                                         \
        mfma_k32(a[fr_][0], B[fc_][0], acc[(FROFF) + fr_][(FCOFF) + fc_]);      \
    acc[(FROFF) + fr_][(FCOFF) + fc_] =                                         \
        mfma_k32(a[fr_][1], B[fc_][1], acc[(FROFF) + fr_][(FCOFF) + fc_]);      \
  }
#define BAR() __builtin_amdgcn_s_barrier()
#define PRIO1() __builtin_amdgcn_s_setprio(1)
#define PRIO0() __builtin_amdgcn_s_setprio(0)

  short8v a[4][2], b01[2][2], b23[2][2];

  // prologue: tile0 all 4 halves + tile1 B-halves; wait first 4 halves landed
  stage_half(A, As + 0 * 8192, tid);
  stage_half(A + (size_t)128 * KK, As + 1 * 8192, tid);
  stage_half(W, Bs + 0 * 8192, tid);
  stage_half(W + (size_t)128 * KK, Bs + 1 * 8192, tid);
  stage_half(W + 64, Bs + 2 * 8192, tid);
  stage_half(W + (size_t)128 * KK + 64, Bs + 3 * 8192, tid);
  asm volatile("s_waitcnt vmcnt(4)" ::: "memory");
  BAR();

#pragma unroll 1
  for (int j = 0; j < ITERS; ++j) {
    const int e = 2 * j, o = e + 1;
    const bool haveE2 = (j + 1 < ITERS);
    // ---- phase 0: tile e reads A fr0-3 + B fc0-1; stage A0(o) -> d1 H0
#pragma unroll
    for (int fr = 0; fr < 4; ++fr) { a[fr][0] = AP(0, fr, 0); a[fr][1] = AP(0, fr, 1); }
#pragma unroll
    for (int fc = 0; fc < 2; ++fc) { b01[fc][0] = BP(0, fc, 0); b01[fc][1] = BP(0, fc, 1); }
    stage_half(A + (size_t)o * 64, As + 2 * 8192, tid);
    BAR(); PRIO1(); MFMA8(0, b01, 0); PRIO0(); BAR();
    // ---- phase 1: reads B fc2-3; stage A1(o) -> d1 H1
#pragma unroll
    for (int fc = 0; fc < 2; ++fc) { b23[fc][0] = BP(0, fc + 2, 0); b23[fc][1] = BP(0, fc + 2, 1); }
    stage_half(A + (size_t)128 * KK + (size_t)o * 64, As + 3 * 8192, tid);
    BAR(); PRIO1(); MFMA8(0, b23, 2); PRIO0(); BAR();
    // ---- phase 2: reads A fr4-7; stage B0(e+2) -> d0 H0
#pragma unroll
    for (int fr = 0; fr < 4; ++fr) { a[fr][0] = AP(0, fr + 4, 0); a[fr][1] = AP(0, fr + 4, 1); }
    if (haveE2) stage_half(W + (size_t)(e + 2) * 64, Bs + 0 * 8192, tid);
    BAR(); PRIO1(); MFMA8(4, b01, 0); PRIO0(); BAR();
    // ---- phase 3: stage B1(e+2) -> d0 H1; counted wait
    if (haveE2) {
      stage_half(W + (size_t)128 * KK + (size_t)(e + 2) * 64, Bs + 1 * 8192, tid);
      asm volatile("s_waitcnt vmcnt(4)" ::: "memory");
    } else {
      asm volatile("s_waitcnt vmcnt(0)" ::: "memory");
    }
    BAR(); PRIO1(); MFMA8(4, b23, 2); PRIO0(); BAR();
    // ---- phase 4: tile o reads A fr0-3 + B fc0-1 (d1); stage A0(e+2) -> d0 H0
#pragma unroll
    for (int fr = 0; fr < 4; ++fr) { a[fr][0] = AP(1, fr, 0); a[fr][1] = AP(1, fr, 1); }
#pragma unroll
    for (int fc = 0; fc < 2; ++fc) { b01[fc][0] = BP(1, fc, 0); b01[fc][1] = BP(1, fc, 1); }
    if (haveE2) stage_half(A + (size_t)(e + 2) * 64, As + 0 * 8192, tid);
    BAR(); PRIO1(); MFMA8(0, b01, 0); PRIO0(); BAR();
    // ---- phase 5: reads B fc2-3 (d1); stage A1(e+2) -> d0 H1
#pragma unroll
    for (int fc = 0; fc < 2; ++fc) { b23[fc][0] = BP(1, fc + 2, 0); b23[fc][1] = BP(1, fc + 2, 1); }
    if (haveE2) stage_half(A + (size_t)128 * KK + (size_t)(e + 2) * 64, As + 1 * 8192, tid);
    BAR(); PRIO1(); MFMA8(0, b23, 2); PRIO0(); BAR();
    // ---- phase 6: reads A fr4-7 (d1); stage B0(o+2) -> d1 H0
#pragma unroll
    for (int fr = 0; fr < 4; ++fr) { a[fr][0] = AP(1, fr + 4, 0); a[fr][1] = AP(1, fr + 4, 1); }
    if (haveE2) stage_half(W + (size_t)(o + 2) * 64, Bs + 2 * 8192, tid);
    BAR(); PRIO1(); MFMA8(4, b01, 0); PRIO0(); BAR();
    // ---- phase 7: stage B1(o+2) -> d1 H1; counted wait (skip entirely on last)
    if (haveE2) {
      stage_half(W + (size_t)128 * KK + (size_t)(o + 2) * 64, Bs + 3 * 8192, tid);
      asm volatile("s_waitcnt vmcnt(4)" ::: "memory");
    }
    BAR(); PRIO1(); MFMA8(4, b23, 2); PRIO0(); BAR();
  }
#undef AP
#undef BP
#undef MFMA8
#undef BAR
#undef PRIO1
#undef PRIO0
}

// ---------------- fused QKV projection (blockIdx.z selects q/k/v) ----------------
// r8: V output layout is now TILED to be the exact LDS image attn wants:
//   per (b,h,kt=key-tile of 64): 4096 u16, addr16 =
//     1024*(dk>>4) + 512*(key>>5) + 128*((key>>2)&3) + 8*(dk&15)
//     + ((key>>4)&1)*4 + (key&3)
//   Inverse-verified: 32(key>>5)+16((key>>4)&1)+4((key>>2)&3)+(key&3) = key.
//   This bakes the PV contraction permutation into memory, so attn's V staging
//   is a pure linear copy and its ds_read is the conflict-free lane*16B pattern.
__global__ __launch_bounds__(512, 2) void proj_gemm(
    const u16* __restrict__ qc, const u16* __restrict__ kc, const u16* __restrict__ vc,
    const u16* __restrict__ Wq, const u16* __restrict__ Wk, const u16* __restrict__ Wv,
    const float* __restrict__ bq, const float* __restrict__ bk, const float* __restrict__ bv,
    u16* __restrict__ Qb, u16* __restrict__ Kb, u16* __restrict__ Vtb) {
  __shared__ __align__(16) u16 As[2 * 2 * 8192];
  __shared__ __align__(16) u16 Bs[2 * 2 * 8192];
  const int z = blockIdx.z;
  const u16* A = (z == 0) ? qc : (z == 1) ? kc : vc;
  const u16* W = (z == 0) ? Wq : (z == 1) ? Wk : Wv;
  const float* bias = (z == 0) ? bq : (z == 1) ? bk : bv;
  const int m0 = blockIdx.x * 256, n0 = blockIdx.y * 256;

  floatx4 acc[8][4] = {};
  gemm256_core(A + (size_t)m0 * KK, W + (size_t)n0 * KK, As, Bs, acc);

  const int tid = threadIdx.x;
  const int w = tid >> 6, lane = tid & 63;
  const int lr = lane & 15, lq = lane >> 4;
  const int wm = w >> 2, wn = w & 3;
  const int row0 = m0 + wm * 128;
  const int col0 = n0 + wn * 64;

  if (z == 2) {
    // V tiled store: rr=0..3 are consecutive keys -> still one packed uint2
#pragma unroll
    for (int fc = 0; fc < 4; ++fc) {
      const int col = col0 + fc * 16 + lr;
      const float bv_ = bias[col];
      const int h = col >> 6, dk = col & 63;
#pragma unroll
      for (int fr = 0; fr < 8; ++fr) {
        const int row = row0 + fr * 16 + lq * 4;
        const int b = row >> 11, s = row & (SS - 1);
        const int kt = s >> 6, key = s & 63;  // key&3 == 0 (row is 4-aligned)
        uint2 pk;
        pk.x = pack2bf(acc[fr][fc][0] + bv_, acc[fr][fc][1] + bv_);
        pk.y = pack2bf(acc[fr][fc][2] + bv_, acc[fr][fc][3] + bv_);
        const size_t addr = (((size_t)(b * HH + h)) * 32 + kt) * 4096 +
                            1024 * (dk >> 4) + 512 * (key >> 5) +
                            128 * ((key >> 2) & 3) + 8 * (dk & 15) +
                            ((key >> 4) & 1) * 4;
        *(uint2*)&Vtb[addr] = pk;
      }
    }
  } else {
    u16* out = (z == 0) ? Qb : Kb;
    const float sc = (z == 0) ? QSCALE : 1.0f;
#pragma unroll
    for (int fc = 0; fc < 4; ++fc) {
      const int col = col0 + fc * 16 + lr;
      const float bv_ = bias[col];
#pragma unroll
      for (int fr = 0; fr < 8; ++fr)
#pragma unroll
        for (int rr = 0; rr < 4; ++rr) {
          const int row = row0 + fr * 16 + lq * 4 + rr;
          out[(size_t)row * NN + col] = f2bf((acc[fr][fc][rr] + bv_) * sc);
        }
    }
  }
}

// ---------------- output GEMM (fp32 store) ----------------
__global__ __launch_bounds__(512, 2) void out_gemm(const u16* __restrict__ A,
                                                   const u16* __restrict__ W,
                                                   const float* __restrict__ bias,
                                                   float* __restrict__ out) {
  __shared__ __align__(16) u16 As[2 * 2 * 8192];
  __shared__ __align__(16) u16 Bs[2 * 2 * 8192];
  const int m0 = blockIdx.x * 256, n0 = blockIdx.y * 256;
  floatx4 acc[8][4] = {};
  gemm256_core(A + (size_t)m0 * KK, W + (size_t)n0 * KK, As, Bs, acc);

  const int tid = threadIdx.x;
  const int w = tid >> 6, lane = tid & 63;
  const int lr = lane & 15, lq = lane >> 4;
  const int wm = w >> 2, wn = w & 3;
  const int row0 = m0 + wm * 128;
  const int col0 = n0 + wn * 64;
#pragma unroll
  for (int fc = 0; fc < 4; ++fc) {
    const int col = col0 + fc * 16 + lr;
    const float bv = bias[col];
#pragma unroll
    for (int fr = 0; fr < 8; ++fr)
#pragma unroll
      for (int rr = 0; rr < 4; ++rr) {
        const int row = row0 + fr * 16 + lq * 4 + rr;
        out[(size_t)row * NN + col] = acc[fr][fc][rr] + bv;
      }
  }
}

// ---------------- flash attention r8: swapped-QK, register P, tiled V ----------------
// QK SWAPPED: sc = mfma(A=K-frag, B=Q-frag) -> D[key][q]; lane (lq,lr) holds
//   P[key=16t+4lq+r][q=lr]. P packs lane-locally into the PV A-frag via the
//   contraction permutation pi (r7-verified numerics): pa[H] slot j =
//   sc[2H+(j>>2)][j&3].
// r8 fixes vs r7 (both counter-diagnosed):
//   1. V B-frag read was a 16-even-bank 2xds_read_b64 (8.4M conflicts). Vtb is
//      now pre-tiled (see proj_gemm) so staging is a LINEAR copy and the read
//      is *(short8v*)&Vs[(2t+H)*512 + lane*8] -- the same lane*16B pattern as
//      the K read, measured conflict-free since r0.
//   2. __launch_bounds__(256,5) starved regalloc (VGPR 48 -> scratch spills,
//      WRITE_SIZE 16->57 MB). Back to (256,4): r6-proven, 128-VGPR budget.
// Loop: 2 barriers + 1 counted vmcnt per iter, K/V both double-buffered.
//   B0 closes reads of buf bf^1; issue K,V(kt+1)->bf^1; vmcnt(4) lands
//   K,V(kt); B1; QK -> softmax/pack -> PV barrier-free.
__global__ __launch_bounds__(256, 4) void attn_kernel(const u16* __restrict__ Q,
                                                      const u16* __restrict__ Kmat,
                                                      const u16* __restrict__ Vt,
                                                      u16* __restrict__ ctx) {
  __shared__ __align__(16) u16 Ks[2][64 * 64];  // chunk 2t+half: key 16t+lr, dk 32*half+8lq+j
  __shared__ __align__(16) u16 Vs[2][64 * 64];  // tiled image: chunk 2t+H, lane*8 (see proj_gemm)
  const int tid = threadIdx.x;
  const int w = tid >> 6, lane = tid & 63;
  const int lr = lane & 15, lq = lane >> 4;
  const int bh = blockIdx.x, b = bh >> 4, h = bh & 15;
  const int q0 = blockIdx.y * 128;

  // Q fragment (dual-use A/B layout): lane holds Q[q=lr(+strip)][dk=8lq+j (+32)]
  short8v qf[2][2];
  {
    const u16* qp = Q + ((size_t)(b * SS + q0 + w * 32 + lr)) * DD + h * 64 + lq * 8;
    qf[0][0] = *(const short8v*)qp;
    qf[0][1] = *(const short8v*)(qp + 32);
    qf[1][0] = *(const short8v*)(qp + 16 * DD);
    qf[1][1] = *(const short8v*)(qp + 16 * DD + 32);
  }
  floatx4 o[2][4] = {};   // o[s][t]: row q=4lq+r, col dk=16t+lr
  float l_part[2] = {};   // per-lane partial denom for q=lr

  const u16* kp = Kmat + ((size_t)(b * SS + w * 16 + lr)) * DD + h * 64 + lq * 8;
  // tiled V: wave w stages chunks 2w,2w+1 of the 4096-u16 tile; pure linear copy
  const u16* vp = Vt + ((size_t)(b * HH + h)) * (32 * 4096) + (2 * w) * 512 + lane * 8;

  // prologue: stage K(0),V(0) -> buf 0
  load_lds16(kp,       &Ks[0][(2 * w) * 512]);
  load_lds16(kp + 32,  &Ks[0][(2 * w + 1) * 512]);
  load_lds16(vp,       &Vs[0][(2 * w) * 512]);
  load_lds16(vp + 512, &Vs[0][(2 * w + 1) * 512]);
  kp += 64 * DD; vp += 4096;

#pragma unroll 1
  for (int kt = 0; kt < SS / 64; ++kt) {
    const int bf = kt & 1;
    const bool haveNext = (kt + 1 < SS / 64);
    __builtin_amdgcn_s_barrier();  // B0: closes QK/PV(kt-1) reads of buf bf^1
    if (haveNext) {
      load_lds16(kp,       &Ks[bf ^ 1][(2 * w) * 512]);
      load_lds16(kp + 32,  &Ks[bf ^ 1][(2 * w + 1) * 512]);
      load_lds16(vp,       &Vs[bf ^ 1][(2 * w) * 512]);
      load_lds16(vp + 512, &Vs[bf ^ 1][(2 * w + 1) * 512]);
      kp += 64 * DD; vp += 4096;
      // W1: outstanding <= [K(kt) 2, V(kt) 2, K(kt+1) 2, V(kt+1) 2]
      //     vmcnt(4) -> K(kt),V(kt) landed
      asm volatile("s_waitcnt vmcnt(4)" ::: "memory");
    } else {
      asm volatile("s_waitcnt vmcnt(0)" ::: "memory");
    }
    __builtin_amdgcn_s_barrier();  // B1: K(kt),V(kt) landed in all waves

    // swapped QK: sc[s][t] = D[key=16t+4lq+r][q=lr] (A=K, B=Q)
    floatx4 sc[2][4] = {};
    __builtin_amdgcn_s_setprio(1);
#pragma unroll
    for (int t = 0; t < 4; ++t) {
      short8v kb0 = *(const short8v*)&Ks[bf][t * 1024 + lane * 8];
      short8v kb1 = *(const short8v*)&Ks[bf][t * 1024 + 512 + lane * 8];
#pragma unroll
      for (int s = 0; s < 2; ++s) {
        sc[s][t] = mfma_k32(kb0, qf[s][0], sc[s][t]);
        sc[s][t] = mfma_k32(kb1, qf[s][1], sc[s][t]);
      }
    }
    __builtin_amdgcn_s_setprio(0);

    // softmax + in-register P pack: pa[s][H] slot j = sc[s][2H+(j>>2)][j&3]
    short8v pa[2][2];
#pragma unroll
    for (int s = 0; s < 2; ++s) {
      float lp = 0.0f;
#pragma unroll
      for (int t = 0; t < 4; ++t)
#pragma unroll
        for (int r = 0; r < 4; ++r) {
          const float e = __builtin_amdgcn_exp2f(sc[s][t][r]);
          sc[s][t][r] = e;
          lp += e;
        }
      l_part[s] += lp;
#pragma unroll
      for (int H = 0; H < 2; ++H) {
        union { u32 u[4]; short8v v; } pb;
        pb.u[0] = pack2bf(sc[s][2 * H][0], sc[s][2 * H][1]);
        pb.u[1] = pack2bf(sc[s][2 * H][2], sc[s][2 * H][3]);
        pb.u[2] = pack2bf(sc[s][2 * H + 1][0], sc[s][2 * H + 1][1]);
        pb.u[3] = pack2bf(sc[s][2 * H + 1][2], sc[s][2 * H + 1][3]);
        pa[s][H] = pb.v;
      }
    }

    // PV: V B-frag is a single conflict-free b128 per (t,H) from the tiled image
    const u16* vsb = &Vs[bf][0];
    __builtin_amdgcn_s_setprio(1);
#pragma unroll
    for (int t = 0; t < 4; ++t) {
      short8v vb0 = *(const short8v*)&vsb[(2 * t) * 512 + lane * 8];
      short8v vb1 = *(const short8v*)&vsb[(2 * t + 1) * 512 + lane * 8];
#pragma unroll
      for (int s = 0; s < 2; ++s) {
        o[s][t] = mfma_k32(pa[s][0], vb0, o[s][t]);
        o[s][t] = mfma_k32(pa[s][1], vb1, o[s][t]);
      }
    }
    __builtin_amdgcn_s_setprio(0);
  }

  // denom: full sum for q=lr, then redistribute to q=4lq+r rows
  float inv[2][4];
#pragma unroll
  for (int s = 0; s < 2; ++s) {
    float l = l_part[s];
    l += __shfl_xor(l, 16);
    l += __shfl_xor(l, 32);
#pragma unroll
    for (int r = 0; r < 4; ++r)
      inv[s][r] = 1.0f / __shfl(l, lq * 4 + r);
  }

#pragma unroll
  for (int s = 0; s < 2; ++s)
#pragma unroll
    for (int r = 0; r < 4; ++r) {
      const int sq = q0 + w * 32 + s * 16 + lq * 4 + r;
      u16* cp = ctx + ((size_t)(b * SS + sq)) * DD + h * 64;
      const float iv = inv[s][r];
#pragma unroll
      for (int t = 0; t < 4; ++t)
        cp[t * 16 + lr] = f2bf(o[s][t][r] * iv);
    }
}

// ---------------- launch ----------------
extern "C" void kernel_launch(void* const* d_in, const int* in_sizes, int n_in,
                              void* d_out, int out_size, void* d_ws, size_t ws_size,
                              hipStream_t stream) {
  const float* query = (const float*)d_in[0];
  const float* key   = (const float*)d_in[1];
  const float* value = (const float*)d_in[2];
  const float* Wq = (const float*)d_in[3];  const float* bq = (const float*)d_in[4];
  const float* Wk = (const float*)d_in[5];  const float* bk = (const float*)d_in[6];
  const float* Wv = (const float*)d_in[7];  const float* bv = (const float*)d_in[8];
  const float* Wo = (const float*)d_in[9];  const float* bo = (const float*)d_in[10];
  float* out = (float*)d_out;

  char* ws = (char*)d_ws;
  size_t off = 0;
  u16* Wb   = (u16*)(ws + off); off += (size_t)4 * DD * DD * 2;  // Wq,Wk,Wv,Wo bf16
  u16* Qb   = (u16*)(ws + off); off += (size_t)MM * DD * 2;      // scaled Q [B,S,D]
  u16* Kb   = (u16*)(ws + off); off += (size_t)MM * DD * 2;      // [B,S,D]
  u16* Vtb  = (u16*)(ws + off); off += (size_t)MM * DD * 2;      // tiled V (see proj_gemm)
  u16* qc   = (u16*)(ws + off);
  u16* ctxb = qc;               off += (size_t)MM * DD * 2;      // ctx aliases qc
  u16* kc = (u16*)d_out;                       // scratch in d_out (overwritten last)
  u16* vc = (u16*)d_out + (size_t)MM * DD;
  u16* Wq_b = Wb, *Wk_b = Wb + (size_t)DD * DD, *Wv_b = Wb + (size_t)2 * DD * DD,
     *Wo_b = Wb + (size_t)3 * DD * DD;

  const int wn = DD * DD, an = MM * DD;
  cvt_w4<<<dim3(wn / 2048, 4), 256, 0, stream>>>(Wq, Wk, Wv, Wo, Wb);
  cvt_a3<<<dim3(an / 2048, 3), 256, 0, stream>>>(query, key, value, qc, kc, vc);

  proj_gemm<<<dim3(MM / 256, NN / 256, 3), 512, 0, stream>>>(
      qc, kc, vc, Wq_b, Wk_b, Wv_b, bq, bk, bv, Qb, Kb, Vtb);

  attn_kernel<<<dim3(BB * HH, SS / 128), 256, 0, stream>>>(Qb, Kb, Vtb, ctxb);

  out_gemm<<<dim3(MM / 256, NN / 256), 512, 0, stream>>>(ctxb, Wo_b, bo, out);
}

// Round 6
// 345.112 us; speedup vs baseline: 1.1355x; 1.0006x over previous
//
#include <hip/hip_runtime.h>

typedef unsigned short u16;
typedef unsigned int u32;
typedef __attribute__((ext_vector_type(8))) short short8v;
typedef __attribute__((ext_vector_type(4))) float floatx4;

#define BB 4
#define SS 2048
#define DD 1024
#define HH 16
#define DKK 64
#define MM (BB * SS)   // 8192
#define KK DD
#define NN DD
// log2(e)/sqrt(DK): folded into Q projection so scores feed exp2 directly
#define QSCALE 0.18033688011112042f

__device__ __forceinline__ u16 f2bf(float f) {
  union { __bf16 h; u16 u; } r; r.h = (__bf16)f; return r.u;
}
__device__ __forceinline__ u32 pack2bf(float a, float b) {
  union { u32 u; __bf16 h[2]; } r;
  r.h[0] = (__bf16)a; r.h[1] = (__bf16)b; return r.u;
}

__device__ __forceinline__ void load_lds16(const void* g, void* l) {
  __builtin_amdgcn_global_load_lds((const __attribute__((address_space(1))) void*)g,
                                   (__attribute__((address_space(3))) void*)l, 16, 0, 0);
}

__device__ __forceinline__ floatx4 mfma_k32(short8v a, short8v b, floatx4 c) {
  return __builtin_amdgcn_mfma_f32_16x16x32_bf16(a, b, c, 0, 0, 0);
}

// ---------------- fp32 -> bf16 converts (fused launches) ----------------
__global__ __launch_bounds__(256) void cvt_w4(const float* __restrict__ w0,
                                              const float* __restrict__ w1,
                                              const float* __restrict__ w2,
                                              const float* __restrict__ w3,
                                              u16* __restrict__ out) {
  const int y = blockIdx.y;
  const float* in = (y == 0) ? w0 : (y == 1) ? w1 : (y == 2) ? w2 : w3;
  u16* o = out + (size_t)y * DD * DD;
  const int i = (blockIdx.x * 256 + threadIdx.x) * 8;
  float4 a = *(const float4*)(in + i);
  float4 b = *(const float4*)(in + i + 4);
  uint4 v;
  v.x = pack2bf(a.x, a.y); v.y = pack2bf(a.z, a.w);
  v.z = pack2bf(b.x, b.y); v.w = pack2bf(b.z, b.w);
  *(uint4*)(o + i) = v;
}

__global__ __launch_bounds__(256) void cvt_a3(const float* __restrict__ a0,
                                              const float* __restrict__ a1,
                                              const float* __restrict__ a2,
                                              u16* __restrict__ o0, u16* __restrict__ o1,
                                              u16* __restrict__ o2) {
  const int y = blockIdx.y;
  const float* in = (y == 0) ? a0 : (y == 1) ? a1 : a2;
  u16* o = (y == 0) ? o0 : (y == 1) ? o1 : o2;
  const int i = (blockIdx.x * 256 + threadIdx.x) * 8;
  float4 a = *(const float4*)(in + i);
  float4 b = *(const float4*)(in + i + 4);
  uint4 v;
  v.x = pack2bf(a.x, a.y); v.y = pack2bf(a.z, a.w);
  v.z = pack2bf(b.x, b.y); v.w = pack2bf(b.z, b.w);
  *(uint4*)(o + i) = v;
}

// ================= 256x256 8-phase GEMM core (T2+T3+T4+T5) =================
// BM=BN=256, BK=64, 2 K-tiles/iteration, 8 waves (2M x 4N), per-wave 128x64.
// LDS: As/Bs each [2 dbuf][2 half][128 rows][64 k] bf16 = 64 KiB -> 128 KiB total.
// Swizzle (T2): element (r,c) stored at c' = c ^ ((r&7)<<3). 16B-group-granular,
// so global_load_lds keeps a LINEAR LDS dest and the SOURCE 16B-group is
// pre-swizzled per lane (rule #21). ds_read of a frag column then spreads the
// 16 rows across 8 distinct 16B slots -> 2-way bank aliasing (free).
// Schedule (ledger-derived; counted waits, never drain-0 in steady state):
//   iter j consumes tile e=2j (dbuf0, phases 0-3) and o=2j+1 (dbuf1, phases 4-7).
//   stages: p0:A0(o) p1:A1(o) p2:B0(e+2) p3:B1(e+2) p4:A0(e+2) p5:A1(e+2)
//           p6:B0(o+2) p7:B1(o+2)   (each 2 x global_load_lds per thread)
//   waits: vmcnt(4) at p3 and p7 (2 half-tiles in flight). Last iter p3: vmcnt(0).
#define NT (KK / 64)     // 16 K-tiles
#define ITERS (NT / 2)   // 8

__device__ __forceinline__ void stage_half(const u16* __restrict__ gsrc, u16* ldst,
                                           int tid) {
#pragma unroll
  for (int L = 0; L < 2; ++L) {
    const int s = L * 512 + tid;
    const int r = s >> 3;
    const int g = (s & 7) ^ (r & 7);   // inverse-swizzled source 16B-group
    load_lds16(gsrc + (size_t)r * KK + g * 8, ldst + s * 8);
  }
}

__device__ __forceinline__ void gemm256_core(const u16* __restrict__ A,  // + m0*KK
                                             const u16* __restrict__ W,  // + n0*KK
                                             u16* As, u16* Bs,           // [2][2][8192]
                                             floatx4 (&acc)[8][4]) {
  const int tid = threadIdx.x;
  const int w = tid >> 6, lane = tid & 63;
  const int wm = w >> 2, wn = w & 3;
  const int wnh = wn >> 1, wno = wn & 1;
  const int lr = lane & 15;
  // swizzled col base for kk=0; kk=1 flips bit5 (c0 ^ 32)
  const int c0 = (((lane >> 2) & 1) << 5) | ((((lane >> 4) ^ lane) & 3) << 3);

#define AP(d, fr, kk) \
  (*(const short8v*)(As + ((d)*2 + wm) * 8192 + ((fr)*16 + lr) * 64 + (c0 ^ ((kk)*32))))
#define BP(d, fc, kk) \
  (*(const short8v*)(Bs + ((d)*2 + wnh) * 8192 + (wno * 64 + (fc)*16 + lr) * 64 + (c0 ^ ((kk)*32))))
#define MFMA8(FROFF, B, FCOFF)                                                  \
  _Pragma("unroll") for (int fr_ = 0; fr_ < 4; ++fr_)                           \
  _Pragma("unroll") for (int fc_ = 0; fc_ < 2; ++fc_) {                         \
    acc[(FROFF) + fr_][(FCOFF) + fc_] =                                         \
        mfma_k32(a[fr_][0], B[fc_][0], acc[(FROFF) + fr_][(FCOFF) + fc_]);      \
    acc[(FROFF) + fr_][(FCOFF) + fc_] =                                         \
        mfma_k32(a[fr_][1], B[fc_][1], acc[(FROFF) + fr_][(FCOFF) + fc_]);      \
  }
#define BAR() __builtin_amdgcn_s_barrier()
#define PRIO1() __builtin_amdgcn_s_setprio(1)
#define PRIO0() __builtin_amdgcn_s_setprio(0)

  short8v a[4][2], b01[2][2], b23[2][2];

  // prologue: tile0 all 4 halves + tile1 B-halves; wait first 4 halves landed
  stage_half(A, As + 0 * 8192, tid);
  stage_half(A + (size_t)128 * KK, As + 1 * 8192, tid);
  stage_half(W, Bs + 0 * 8192, tid);
  stage_half(W + (size_t)128 * KK, Bs + 1 * 8192, tid);
  stage_half(W + 64, Bs + 2 * 8192, tid);
  stage_half(W + (size_t)128 * KK + 64, Bs + 3 * 8192, tid);
  asm volatile("s_waitcnt vmcnt(4)" ::: "memory");
  BAR();

#pragma unroll 1
  for (int j = 0; j < ITERS; ++j) {
    const int e = 2 * j, o = e + 1;
    const bool haveE2 = (j + 1 < ITERS);
    // ---- phase 0: tile e reads A fr0-3 + B fc0-1; stage A0(o) -> d1 H0
#pragma unroll
    for (int fr = 0; fr < 4; ++fr) { a[fr][0] = AP(0, fr, 0); a[fr][1] = AP(0, fr, 1); }
#pragma unroll
    for (int fc = 0; fc < 2; ++fc) { b01[fc][0] = BP(0, fc, 0); b01[fc][1] = BP(0, fc, 1); }
    stage_half(A + (size_t)o * 64, As + 2 * 8192, tid);
    BAR(); PRIO1(); MFMA8(0, b01, 0); PRIO0(); BAR();
    // ---- phase 1: reads B fc2-3; stage A1(o) -> d1 H1
#pragma unroll
    for (int fc = 0; fc < 2; ++fc) { b23[fc][0] = BP(0, fc + 2, 0); b23[fc][1] = BP(0, fc + 2, 1); }
    stage_half(A + (size_t)128 * KK + (size_t)o * 64, As + 3 * 8192, tid);
    BAR(); PRIO1(); MFMA8(0, b23, 2); PRIO0(); BAR();
    // ---- phase 2: reads A fr4-7; stage B0(e+2) -> d0 H0
#pragma unroll
    for (int fr = 0; fr < 4; ++fr) { a[fr][0] = AP(0, fr + 4, 0); a[fr][1] = AP(0, fr + 4, 1); }
    if (haveE2) stage_half(W + (size_t)(e + 2) * 64, Bs + 0 * 8192, tid);
    BAR(); PRIO1(); MFMA8(4, b01, 0); PRIO0(); BAR();
    // ---- phase 3: stage B1(e+2) -> d0 H1; counted wait
    if (haveE2) {
      stage_half(W + (size_t)128 * KK + (size_t)(e + 2) * 64, Bs + 1 * 8192, tid);
      asm volatile("s_waitcnt vmcnt(4)" ::: "memory");
    } else {
      asm volatile("s_waitcnt vmcnt(0)" ::: "memory");
    }
    BAR(); PRIO1(); MFMA8(4, b23, 2); PRIO0(); BAR();
    // ---- phase 4: tile o reads A fr0-3 + B fc0-1 (d1); stage A0(e+2) -> d0 H0
#pragma unroll
    for (int fr = 0; fr < 4; ++fr) { a[fr][0] = AP(1, fr, 0); a[fr][1] = AP(1, fr, 1); }
#pragma unroll
    for (int fc = 0; fc < 2; ++fc) { b01[fc][0] = BP(1, fc, 0); b01[fc][1] = BP(1, fc, 1); }
    if (haveE2) stage_half(A + (size_t)(e + 2) * 64, As + 0 * 8192, tid);
    BAR(); PRIO1(); MFMA8(0, b01, 0); PRIO0(); BAR();
    // ---- phase 5: reads B fc2-3 (d1); stage A1(e+2) -> d0 H1
#pragma unroll
    for (int fc = 0; fc < 2; ++fc) { b23[fc][0] = BP(1, fc + 2, 0); b23[fc][1] = BP(1, fc + 2, 1); }
    if (haveE2) stage_half(A + (size_t)128 * KK + (size_t)(e + 2) * 64, As + 1 * 8192, tid);
    BAR(); PRIO1(); MFMA8(0, b23, 2); PRIO0(); BAR();
    // ---- phase 6: reads A fr4-7 (d1); stage B0(o+2) -> d1 H0
#pragma unroll
    for (int fr = 0; fr < 4; ++fr) { a[fr][0] = AP(1, fr + 4, 0); a[fr][1] = AP(1, fr + 4, 1); }
    if (haveE2) stage_half(W + (size_t)(o + 2) * 64, Bs + 2 * 8192, tid);
    BAR(); PRIO1(); MFMA8(4, b01, 0); PRIO0(); BAR();
    // ---- phase 7: stage B1(o+2) -> d1 H1; counted wait (skip entirely on last)
    if (haveE2) {
      stage_half(W + (size_t)128 * KK + (size_t)(o + 2) * 64, Bs + 3 * 8192, tid);
      asm volatile("s_waitcnt vmcnt(4)" ::: "memory");
    }
    BAR(); PRIO1(); MFMA8(4, b23, 2); PRIO0(); BAR();
  }
#undef AP
#undef BP
#undef MFMA8
#undef BAR
#undef PRIO1
#undef PRIO0
}

// ---------------- fused QKV projection (blockIdx.z selects q/k/v) ----------------
// V output layout TILED to be the exact LDS image attn wants (r8-verified):
//   per (b,h,kt=key-tile of 64): 4096 u16, addr16 =
//     1024*(dk>>4) + 512*(key>>5) + 128*((key>>2)&3) + 8*(dk&15)
//     + ((key>>4)&1)*4 + (key&3)
__global__ __launch_bounds__(512, 2) void proj_gemm(
    const u16* __restrict__ qc, const u16* __restrict__ kc, const u16* __restrict__ vc,
    const u16* __restrict__ Wq, const u16* __restrict__ Wk, const u16* __restrict__ Wv,
    const float* __restrict__ bq, const float* __restrict__ bk, const float* __restrict__ bv,
    u16* __restrict__ Qb, u16* __restrict__ Kb, u16* __restrict__ Vtb) {
  __shared__ __align__(16) u16 As[2 * 2 * 8192];
  __shared__ __align__(16) u16 Bs[2 * 2 * 8192];
  const int z = blockIdx.z;
  const u16* A = (z == 0) ? qc : (z == 1) ? kc : vc;
  const u16* W = (z == 0) ? Wq : (z == 1) ? Wk : Wv;
  const float* bias = (z == 0) ? bq : (z == 1) ? bk : bv;
  const int m0 = blockIdx.x * 256, n0 = blockIdx.y * 256;

  floatx4 acc[8][4] = {};
  gemm256_core(A + (size_t)m0 * KK, W + (size_t)n0 * KK, As, Bs, acc);

  const int tid = threadIdx.x;
  const int w = tid >> 6, lane = tid & 63;
  const int lr = lane & 15, lq = lane >> 4;
  const int wm = w >> 2, wn = w & 3;
  const int row0 = m0 + wm * 128;
  const int col0 = n0 + wn * 64;

  if (z == 2) {
    // V tiled store: rr=0..3 are consecutive keys -> still one packed uint2
#pragma unroll
    for (int fc = 0; fc < 4; ++fc) {
      const int col = col0 + fc * 16 + lr;
      const float bv_ = bias[col];
      const int h = col >> 6, dk = col & 63;
#pragma unroll
      for (int fr = 0; fr < 8; ++fr) {
        const int row = row0 + fr * 16 + lq * 4;
        const int b = row >> 11, s = row & (SS - 1);
        const int kt = s >> 6, key = s & 63;  // key&3 == 0 (row is 4-aligned)
        uint2 pk;
        pk.x = pack2bf(acc[fr][fc][0] + bv_, acc[fr][fc][1] + bv_);
        pk.y = pack2bf(acc[fr][fc][2] + bv_, acc[fr][fc][3] + bv_);
        const size_t addr = (((size_t)(b * HH + h)) * 32 + kt) * 4096 +
                            1024 * (dk >> 4) + 512 * (key >> 5) +
                            128 * ((key >> 2) & 3) + 8 * (dk & 15) +
                            ((key >> 4) & 1) * 4;
        *(uint2*)&Vtb[addr] = pk;
      }
    }
  } else {
    u16* out = (z == 0) ? Qb : Kb;
    const float sc = (z == 0) ? QSCALE : 1.0f;
#pragma unroll
    for (int fc = 0; fc < 4; ++fc) {
      const int col = col0 + fc * 16 + lr;
      const float bv_ = bias[col];
#pragma unroll
      for (int fr = 0; fr < 8; ++fr)
#pragma unroll
        for (int rr = 0; rr < 4; ++rr) {
          const int row = row0 + fr * 16 + lq * 4 + rr;
          out[(size_t)row * NN + col] = f2bf((acc[fr][fc][rr] + bv_) * sc);
        }
    }
  }
}

// ---------------- output GEMM (fp32 store) ----------------
__global__ __launch_bounds__(512, 2) void out_gemm(const u16* __restrict__ A,
                                                   const u16* __restrict__ W,
                                                   const float* __restrict__ bias,
                                                   float* __restrict__ out) {
  __shared__ __align__(16) u16 As[2 * 2 * 8192];
  __shared__ __align__(16) u16 Bs[2 * 2 * 8192];
  const int m0 = blockIdx.x * 256, n0 = blockIdx.y * 256;
  floatx4 acc[8][4] = {};
  gemm256_core(A + (size_t)m0 * KK, W + (size_t)n0 * KK, As, Bs, acc);

  const int tid = threadIdx.x;
  const int w = tid >> 6, lane = tid & 63;
  const int lr = lane & 15, lq = lane >> 4;
  const int wm = w >> 2, wn = w & 3;
  const int row0 = m0 + wm * 128;
  const int col0 = n0 + wn * 64;
#pragma unroll
  for (int fc = 0; fc < 4; ++fc) {
    const int col = col0 + fc * 16 + lr;
    const float bv = bias[col];
#pragma unroll
    for (int fr = 0; fr < 8; ++fr)
#pragma unroll
      for (int rr = 0; rr < 4; ++rr) {
        const int row = row0 + fr * 16 + lq * 4 + rr;
        out[(size_t)row * NN + col] = acc[fr][fc][rr] + bv;
      }
  }
}

// ---------------- flash attention r9: cross-iteration PV pipeline ----------------
// r8 counters: MfmaUtil 30 / VALUBusy 48 / ~50% no-issue -- the per-wave chain
// barrier -> QK -> exp(quarter-rate, ~256cy) -> pack -> PV -> barrier is serial.
// r9: hold packed P one iteration; at iter kt issue QK(kt) THEN PV(kt-1) (32
// back-to-back MFMAs) while exp/pack(kt) (independent of PV(kt-1)) fills VALU.
// Requires V(kt-1) live while V(kt+1) stages -> Vs TRIPLE buffer (Ks stays 2).
// LDS 2*8K + 3*8K = 40960 B -> still 4 blocks/CU.
// Hazards (all ledger-checked): K(kt+1) overwrites Ks[(kt-1)&1], last read
// QK(kt-1) before B0 of iter kt; V(kt+1)->Vs[(kt+1)%3] overwrites V(kt-2), last
// read PV(kt-2) at iter kt-1 before B0. Waits: 8 loads in flight, vmcnt(4)
// lands K(kt),V(kt); PV needs only V(kt-1) (landed at iter kt-1's wait).
// Peel kt=0 (no PV); final PV(31) after the loop.
__global__ __launch_bounds__(256, 4) void attn_kernel(const u16* __restrict__ Q,
                                                      const u16* __restrict__ Kmat,
                                                      const u16* __restrict__ Vt,
                                                      u16* __restrict__ ctx) {
  __shared__ __align__(16) u16 Ks[2][4096];  // chunk 2t+half: key 16t+lr, dk 32*half+8lq+j
  __shared__ __align__(16) u16 Vs[3][4096];  // tiled image: chunk 2t+H, lane*8
  const int tid = threadIdx.x;
  const int w = tid >> 6, lane = tid & 63;
  const int lr = lane & 15, lq = lane >> 4;
  const int bh = blockIdx.x, b = bh >> 4, h = bh & 15;
  const int q0 = blockIdx.y * 128;

  // Q fragment (dual-use A/B layout): lane holds Q[q=lr(+strip)][dk=8lq+j (+32)]
  short8v qf[2][2];
  {
    const u16* qp = Q + ((size_t)(b * SS + q0 + w * 32 + lr)) * DD + h * 64 + lq * 8;
    qf[0][0] = *(const short8v*)qp;
    qf[0][1] = *(const short8v*)(qp + 32);
    qf[1][0] = *(const short8v*)(qp + 16 * DD);
    qf[1][1] = *(const short8v*)(qp + 16 * DD + 32);
  }
  floatx4 o[2][4] = {};   // o[s][t]: row q=4lq+r, col dk=16t+lr
  float l_part[2] = {};   // per-lane partial denom for q=lr
  short8v pa[2][2];       // packed P of the PREVIOUS tile (pipeline register)

  const u16* kp = Kmat + ((size_t)(b * SS + w * 16 + lr)) * DD + h * 64 + lq * 8;
  const u16* vp = Vt + ((size_t)(b * HH + h)) * (32 * 4096) + (2 * w) * 512 + lane * 8;

// helper macros over fixed local names (sc, pa, o, qf, lane)
#define QK_BLOCK(KSB)                                                        \
  _Pragma("unroll") for (int t = 0; t < 4; ++t) {                            \
    short8v kb0 = *(const short8v*)&(KSB)[t * 1024 + lane * 8];              \
    short8v kb1 = *(const short8v*)&(KSB)[t * 1024 + 512 + lane * 8];        \
    _Pragma("unroll") for (int s = 0; s < 2; ++s) {                          \
      sc[s][t] = mfma_k32(kb0, qf[s][0], sc[s][t]);                          \
      sc[s][t] = mfma_k32(kb1, qf[s][1], sc[s][t]);                          \
    }                                                                        \
  }
#define PV_BLOCK(VSB)                                                        \
  _Pragma("unroll") for (int t = 0; t < 4; ++t) {                            \
    short8v vb0 = *(const short8v*)&(VSB)[(2 * t) * 512 + lane * 8];         \
    short8v vb1 = *(const short8v*)&(VSB)[(2 * t + 1) * 512 + lane * 8];     \
    _Pragma("unroll") for (int s = 0; s < 2; ++s) {                          \
      o[s][t] = mfma_k32(pa[s][0], vb0, o[s][t]);                            \
      o[s][t] = mfma_k32(pa[s][1], vb1, o[s][t]);                            \
    }                                                                        \
  }
#define SM_BLOCK()                                                           \
  _Pragma("unroll") for (int s = 0; s < 2; ++s) {                            \
    float lp = 0.0f;                                                         \
    _Pragma("unroll") for (int t = 0; t < 4; ++t)                            \
      _Pragma("unroll") for (int r = 0; r < 4; ++r) {                        \
        const float e = __builtin_amdgcn_exp2f(sc[s][t][r]);                 \
        sc[s][t][r] = e;                                                     \
        lp += e;                                                             \
      }                                                                      \
    l_part[s] += lp;                                                         \
    _Pragma("unroll") for (int H = 0; H < 2; ++H) {                          \
      union { u32 u[4]; short8v v; } pb;                                     \
      pb.u[0] = pack2bf(sc[s][2 * H][0], sc[s][2 * H][1]);                   \
      pb.u[1] = pack2bf(sc[s][2 * H][2], sc[s][2 * H][3]);                   \
      pb.u[2] = pack2bf(sc[s][2 * H + 1][0], sc[s][2 * H + 1][1]);           \
      pb.u[3] = pack2bf(sc[s][2 * H + 1][2], sc[s][2 * H + 1][3]);           \
      pa[s][H] = pb.v;                                                       \
    }                                                                        \
  }

  // prologue: stage tiles 0 and 1
  load_lds16(kp,       &Ks[0][(2 * w) * 512]);
  load_lds16(kp + 32,  &Ks[0][(2 * w + 1) * 512]);
  load_lds16(vp,       &Vs[0][(2 * w) * 512]);
  load_lds16(vp + 512, &Vs[0][(2 * w + 1) * 512]);
  kp += 64 * DD; vp += 4096;
  load_lds16(kp,       &Ks[1][(2 * w) * 512]);
  load_lds16(kp + 32,  &Ks[1][(2 * w + 1) * 512]);
  load_lds16(vp,       &Vs[1][(2 * w) * 512]);
  load_lds16(vp + 512, &Vs[1][(2 * w + 1) * 512]);
  kp += 64 * DD; vp += 4096;
  asm volatile("s_waitcnt vmcnt(4)" ::: "memory");  // tile 0 landed
  __builtin_amdgcn_s_barrier();

  // peel kt=0: QK + softmax only (fills pa)
  {
    floatx4 sc[2][4] = {};
    __builtin_amdgcn_s_setprio(1);
    QK_BLOCK(Ks[0])
    __builtin_amdgcn_s_setprio(0);
    SM_BLOCK()
  }

  int vprev = 0, vcur = 1, vnxt = 2;
#pragma unroll 1
  for (int kt = 1; kt < SS / 64; ++kt) {
    const bool haveNext = (kt + 1 < SS / 64);
    __builtin_amdgcn_s_barrier();  // B0: closes QK(kt-1)/PV(kt-2) reads
    if (haveNext) {
      load_lds16(kp,       &Ks[(kt + 1) & 1][(2 * w) * 512]);
      load_lds16(kp + 32,  &Ks[(kt + 1) & 1][(2 * w + 1) * 512]);
      load_lds16(vp,       &Vs[vnxt][(2 * w) * 512]);
      load_lds16(vp + 512, &Vs[vnxt][(2 * w + 1) * 512]);
      kp += 64 * DD; vp += 4096;
      // 8 in flight max -> vmcnt(4) lands K(kt),V(kt)
      asm volatile("s_waitcnt vmcnt(4)" ::: "memory");
    } else {
      asm volatile("s_waitcnt vmcnt(0)" ::: "memory");
    }
    __builtin_amdgcn_s_barrier();  // B1: K(kt),V(kt) visible to all waves

    floatx4 sc[2][4] = {};
    const u16* ksb = &Ks[kt & 1][0];
    const u16* vsb = &Vs[vprev][0];
    __builtin_amdgcn_s_setprio(1);
    QK_BLOCK(ksb)   // matrix pipe: QK(kt)
    PV_BLOCK(vsb)   // matrix pipe: PV(kt-1) -- overlaps exp below via scheduler
    __builtin_amdgcn_s_setprio(0);
    SM_BLOCK()      // VALU: exp/pack(kt) -> new pa (independent of PV above)

    vprev = vcur; vcur = vnxt; vnxt = (vnxt + 1 == 3) ? 0 : vnxt + 1;
  }

  // final PV(31): reads Vs[31 % 3] == vprev after the last rotation
  {
    const u16* vsb = &Vs[vprev][0];
    __builtin_amdgcn_s_setprio(1);
    PV_BLOCK(vsb)
    __builtin_amdgcn_s_setprio(0);
  }
#undef QK_BLOCK
#undef PV_BLOCK
#undef SM_BLOCK

  // denom: full sum for q=lr, then redistribute to q=4lq+r rows
  float inv[2][4];
#pragma unroll
  for (int s = 0; s < 2; ++s) {
    float l = l_part[s];
    l += __shfl_xor(l, 16);
    l += __shfl_xor(l, 32);
#pragma unroll
    for (int r = 0; r < 4; ++r)
      inv[s][r] = 1.0f / __shfl(l, lq * 4 + r);
  }

#pragma unroll
  for (int s = 0; s < 2; ++s)
#pragma unroll
    for (int r = 0; r < 4; ++r) {
      const int sq = q0 + w * 32 + s * 16 + lq * 4 + r;
      u16* cp = ctx + ((size_t)(b * SS + sq)) * DD + h * 64;
      const float iv = inv[s][r];
#pragma unroll
      for (int t = 0; t < 4; ++t)
        cp[t * 16 + lr] = f2bf(o[s][t][r] * iv);
    }
}

// ---------------- launch ----------------
extern "C" void kernel_launch(void* const* d_in, const int* in_sizes, int n_in,
                              void* d_out, int out_size, void* d_ws, size_t ws_size,
                              hipStream_t stream) {
  const float* query = (const float*)d_in[0];
  const float* key   = (const float*)d_in[1];
  const float* value = (const float*)d_in[2];
  const float* Wq = (const float*)d_in[3];  const float* bq = (const float*)d_in[4];
  const float* Wk = (const float*)d_in[5];  const float* bk = (const float*)d_in[6];
  const float* Wv = (const float*)d_in[7];  const float* bv = (const float*)d_in[8];
  const float* Wo = (const float*)d_in[9];  const float* bo = (const float*)d_in[10];
  float* out = (float*)d_out;

  char* ws = (char*)d_ws;
  size_t off = 0;
  u16* Wb   = (u16*)(ws + off); off += (size_t)4 * DD * DD * 2;  // Wq,Wk,Wv,Wo bf16
  u16* Qb   = (u16*)(ws + off); off += (size_t)MM * DD * 2;      // scaled Q [B,S,D]
  u16* Kb   = (u16*)(ws + off); off += (size_t)MM * DD * 2;      // [B,S,D]
  u16* Vtb  = (u16*)(ws + off); off += (size_t)MM * DD * 2;      // tiled V (see proj_gemm)
  u16* qc   = (u16*)(ws + off);
  u16* ctxb = qc;               off += (size_t)MM * DD * 2;      // ctx aliases qc
  u16* kc = (u16*)d_out;                       // scratch in d_out (overwritten last)
  u16* vc = (u16*)d_out + (size_t)MM * DD;
  u16* Wq_b = Wb, *Wk_b = Wb + (size_t)DD * DD, *Wv_b = Wb + (size_t)2 * DD * DD,
     *Wo_b = Wb + (size_t)3 * DD * DD;

  const int wn = DD * DD, an = MM * DD;
  cvt_w4<<<dim3(wn / 2048, 4), 256, 0, stream>>>(Wq, Wk, Wv, Wo, Wb);
  cvt_a3<<<dim3(an / 2048, 3), 256, 0, stream>>>(query, key, value, qc, kc, vc);

  proj_gemm<<<dim3(MM / 256, NN / 256, 3), 512, 0, stream>>>(
      qc, kc, vc, Wq_b, Wk_b, Wv_b, bq, bk, bv, Qb, Kb, Vtb);

  attn_kernel<<<dim3(BB * HH, SS / 128), 256, 0, stream>>>(Qb, Kb, Vtb, ctxb);

  out_gemm<<<dim3(MM / 256, NN / 256), 512, 0, stream>>>(ctxb, Wo_b, bo, out);
}

// Round 7
// 343.734 us; speedup vs baseline: 1.1400x; 1.0040x over previous
//
#include <hip/hip_runtime.h>

typedef unsigned short u16;
typedef unsigned int u32;
typedef __attribute__((ext_vector_type(8))) short short8v;
typedef __attribute__((ext_vector_type(4))) float floatx4;

#define BB 4
#define SS 2048
#define DD 1024
#define HH 16
#define DKK 64
#define MM (BB * SS)   // 8192
#define KK DD
#define NN DD
// log2(e)/sqrt(DK): folded into Q projection so scores feed exp2 directly
#define QSCALE 0.18033688011112042f

__device__ __forceinline__ u16 f2bf(float f) {
  union { __bf16 h; u16 u; } r; r.h = (__bf16)f; return r.u;
}
__device__ __forceinline__ u32 pack2bf(float a, float b) {
  union { u32 u; __bf16 h[2]; } r;
  r.h[0] = (__bf16)a; r.h[1] = (__bf16)b; return r.u;
}

__device__ __forceinline__ void load_lds16(const void* g, void* l) {
  __builtin_amdgcn_global_load_lds((const __attribute__((address_space(1))) void*)g,
                                   (__attribute__((address_space(3))) void*)l, 16, 0, 0);
}

__device__ __forceinline__ floatx4 mfma_k32(short8v a, short8v b, floatx4 c) {
  return __builtin_amdgcn_mfma_f32_16x16x32_bf16(a, b, c, 0, 0, 0);
}

// ---------------- fp32 -> bf16 converts (fused launches) ----------------
__global__ __launch_bounds__(256) void cvt_w4(const float* __restrict__ w0,
                                              const float* __restrict__ w1,
                                              const float* __restrict__ w2,
                                              const float* __restrict__ w3,
                                              u16* __restrict__ out) {
  const int y = blockIdx.y;
  const float* in = (y == 0) ? w0 : (y == 1) ? w1 : (y == 2) ? w2 : w3;
  u16* o = out + (size_t)y * DD * DD;
  const int i = (blockIdx.x * 256 + threadIdx.x) * 8;
  float4 a = *(const float4*)(in + i);
  float4 b = *(const float4*)(in + i + 4);
  uint4 v;
  v.x = pack2bf(a.x, a.y); v.y = pack2bf(a.z, a.w);
  v.z = pack2bf(b.x, b.y); v.w = pack2bf(b.z, b.w);
  *(uint4*)(o + i) = v;
}

__global__ __launch_bounds__(256) void cvt_a3(const float* __restrict__ a0,
                                              const float* __restrict__ a1,
                                              const float* __restrict__ a2,
                                              u16* __restrict__ o0, u16* __restrict__ o1,
                                              u16* __restrict__ o2) {
  const int y = blockIdx.y;
  const float* in = (y == 0) ? a0 : (y == 1) ? a1 : a2;
  u16* o = (y == 0) ? o0 : (y == 1) ? o1 : o2;
  const int i = (blockIdx.x * 256 + threadIdx.x) * 8;
  float4 a = *(const float4*)(in + i);
  float4 b = *(const float4*)(in + i + 4);
  uint4 v;
  v.x = pack2bf(a.x, a.y); v.y = pack2bf(a.z, a.w);
  v.z = pack2bf(b.x, b.y); v.w = pack2bf(b.z, b.w);
  *(uint4*)(o + i) = v;
}

// ================= 256x256 8-phase GEMM core (T2+T3+T4+T5) =================
// BM=BN=256, BK=64, 2 K-tiles/iteration, 8 waves (2M x 4N), per-wave 128x64.
// LDS: As/Bs each [2 dbuf][2 half][128 rows][64 k] bf16 = 64 KiB -> 128 KiB total.
// Swizzle (T2): element (r,c) stored at c' = c ^ ((r&7)<<3). 16B-group-granular,
// so global_load_lds keeps a LINEAR LDS dest and the SOURCE 16B-group is
// pre-swizzled per lane (rule #21). ds_read of a frag column then spreads the
// 16 rows across 8 distinct 16B slots -> 2-way bank aliasing (free).
// Schedule (ledger-derived; counted waits, never drain-0 in steady state):
//   iter j consumes tile e=2j (dbuf0, phases 0-3) and o=2j+1 (dbuf1, phases 4-7).
//   stages: p0:A0(o) p1:A1(o) p2:B0(e+2) p3:B1(e+2) p4:A0(e+2) p5:A1(e+2)
//           p6:B0(o+2) p7:B1(o+2)   (each 2 x global_load_lds per thread)
//   waits: vmcnt(4) at p3 and p7 (2 half-tiles in flight). Last iter p3: vmcnt(0).
#define NT (KK / 64)     // 16 K-tiles
#define ITERS (NT / 2)   // 8

__device__ __forceinline__ void stage_half(const u16* __restrict__ gsrc, u16* ldst,
                                           int tid) {
#pragma unroll
  for (int L = 0; L < 2; ++L) {
    const int s = L * 512 + tid;
    const int r = s >> 3;
    const int g = (s & 7) ^ (r & 7);   // inverse-swizzled source 16B-group
    load_lds16(gsrc + (size_t)r * KK + g * 8, ldst + s * 8);
  }
}

__device__ __forceinline__ void gemm256_core(const u16* __restrict__ A,  // + m0*KK
                                             const u16* __restrict__ W,  // + n0*KK
                                             u16* As, u16* Bs,           // [2][2][8192]
                                             floatx4 (&acc)[8][4]) {
  const int tid = threadIdx.x;
  const int w = tid >> 6, lane = tid & 63;
  const int wm = w >> 2, wn = w & 3;
  const int wnh = wn >> 1, wno = wn & 1;
  const int lr = lane & 15;
  // swizzled col base for kk=0; kk=1 flips bit5 (c0 ^ 32)
  const int c0 = (((lane >> 2) & 1) << 5) | ((((lane >> 4) ^ lane) & 3) << 3);

#define AP(d, fr, kk) \
  (*(const short8v*)(As + ((d)*2 + wm) * 8192 + ((fr)*16 + lr) * 64 + (c0 ^ ((kk)*32))))
#define BP(d, fc, kk) \
  (*(const short8v*)(Bs + ((d)*2 + wnh) * 8192 + (wno * 64 + (fc)*16 + lr) * 64 + (c0 ^ ((kk)*32))))
#define MFMA8(FROFF, B, FCOFF)                                                  \
  _Pragma("unroll") for (int fr_ = 0; fr_ < 4; ++fr_)                           \
  _Pragma("unroll") for (int fc_ = 0; fc_ < 2; ++fc_) {                         \
    acc[(FROFF) + fr_][(FCOFF) + fc_] =                                         \
        mfma_k32(a[fr_][0], B[fc_][0], acc[(FROFF) + fr_][(FCOFF) + fc_]);      \
    acc[(FROFF) + fr_][(FCOFF) + fc_] =                                         \
        mfma_k32(a[fr_][1], B[fc_][1], acc[(FROFF) + fr_][(FCOFF) + fc_]);      \
  }
#define BAR() __builtin_amdgcn_s_barrier()
#define PRIO1() __builtin_amdgcn_s_setprio(1)
#define PRIO0() __builtin_amdgcn_s_setprio(0)

  short8v a[4][2], b01[2][2], b23[2][2];

  // prologue: tile0 all 4 halves + tile1 B-halves; wait first 4 halves landed
  stage_half(A, As + 0 * 8192, tid);
  stage_half(A + (size_t)128 * KK, As + 1 * 8192, tid);
  stage_half(W, Bs + 0 * 8192, tid);
  stage_half(W + (size_t)128 * KK, Bs + 1 * 8192, tid);
  stage_half(W + 64, Bs + 2 * 8192, tid);
  stage_half(W + (size_t)128 * KK + 64, Bs + 3 * 8192, tid);
  asm volatile("s_waitcnt vmcnt(4)" ::: "memory");
  BAR();

#pragma unroll 1
  for (int j = 0; j < ITERS; ++j) {
    const int e = 2 * j, o = e + 1;
    const bool haveE2 = (j + 1 < ITERS);
    // ---- phase 0: tile e reads A fr0-3 + B fc0-1; stage A0(o) -> d1 H0
#pragma unroll
    for (int fr = 0; fr < 4; ++fr) { a[fr][0] = AP(0, fr, 0); a[fr][1] = AP(0, fr, 1); }
#pragma unroll
    for (int fc = 0; fc < 2; ++fc) { b01[fc][0] = BP(0, fc, 0); b01[fc][1] = BP(0, fc, 1); }
    stage_half(A + (size_t)o * 64, As + 2 * 8192, tid);
    BAR(); PRIO1(); MFMA8(0, b01, 0); PRIO0(); BAR();
    // ---- phase 1: reads B fc2-3; stage A1(o) -> d1 H1
#pragma unroll
    for (int fc = 0; fc < 2; ++fc) { b23[fc][0] = BP(0, fc + 2, 0); b23[fc][1] = BP(0, fc + 2, 1); }
    stage_half(A + (size_t)128 * KK + (size_t)o * 64, As + 3 * 8192, tid);
    BAR(); PRIO1(); MFMA8(0, b23, 2); PRIO0(); BAR();
    // ---- phase 2: reads A fr4-7; stage B0(e+2) -> d0 H0
#pragma unroll
    for (int fr = 0; fr < 4; ++fr) { a[fr][0] = AP(0, fr + 4, 0); a[fr][1] = AP(0, fr + 4, 1); }
    if (haveE2) stage_half(W + (size_t)(e + 2) * 64, Bs + 0 * 8192, tid);
    BAR(); PRIO1(); MFMA8(4, b01, 0); PRIO0(); BAR();
    // ---- phase 3: stage B1(e+2) -> d0 H1; counted wait
    if (haveE2) {
      stage_half(W + (size_t)128 * KK + (size_t)(e + 2) * 64, Bs + 1 * 8192, tid);
      asm volatile("s_waitcnt vmcnt(4)" ::: "memory");
    } else {
      asm volatile("s_waitcnt vmcnt(0)" ::: "memory");
    }
    BAR(); PRIO1(); MFMA8(4, b23, 2); PRIO0(); BAR();
    // ---- phase 4: tile o reads A fr0-3 + B fc0-1 (d1); stage A0(e+2) -> d0 H0
#pragma unroll
    for (int fr = 0; fr < 4; ++fr) { a[fr][0] = AP(1, fr, 0); a[fr][1] = AP(1, fr, 1); }
#pragma unroll
    for (int fc = 0; fc < 2; ++fc) { b01[fc][0] = BP(1, fc, 0); b01[fc][1] = BP(1, fc, 1); }
    if (haveE2) stage_half(A + (size_t)(e + 2) * 64, As + 0 * 8192, tid);
    BAR(); PRIO1(); MFMA8(0, b01, 0); PRIO0(); BAR();
    // ---- phase 5: reads B fc2-3 (d1); stage A1(e+2) -> d0 H1
#pragma unroll
    for (int fc = 0; fc < 2; ++fc) { b23[fc][0] = BP(1, fc + 2, 0); b23[fc][1] = BP(1, fc + 2, 1); }
    if (haveE2) stage_half(A + (size_t)128 * KK + (size_t)(e + 2) * 64, As + 1 * 8192, tid);
    BAR(); PRIO1(); MFMA8(0, b23, 2); PRIO0(); BAR();
    // ---- phase 6: reads A fr4-7 (d1); stage B0(o+2) -> d1 H0
#pragma unroll
    for (int fr = 0; fr < 4; ++fr) { a[fr][0] = AP(1, fr + 4, 0); a[fr][1] = AP(1, fr + 4, 1); }
    if (haveE2) stage_half(W + (size_t)(o + 2) * 64, Bs + 2 * 8192, tid);
    BAR(); PRIO1(); MFMA8(4, b01, 0); PRIO0(); BAR();
    // ---- phase 7: stage B1(o+2) -> d1 H1; counted wait (skip entirely on last)
    if (haveE2) {
      stage_half(W + (size_t)128 * KK + (size_t)(o + 2) * 64, Bs + 3 * 8192, tid);
      asm volatile("s_waitcnt vmcnt(4)" ::: "memory");
    }
    BAR(); PRIO1(); MFMA8(4, b23, 2); PRIO0(); BAR();
  }
#undef AP
#undef BP
#undef MFMA8
#undef BAR
#undef PRIO1
#undef PRIO0
}

// ---------------- fused QKV projection (blockIdx.z selects q/k/v) ----------------
// V output layout TILED to be the exact LDS image attn wants (r8-verified):
//   per (b,h,kt=key-tile of 64): 4096 u16, addr16 =
//     1024*(dk>>4) + 512*(key>>5) + 128*((key>>2)&3) + 8*(dk&15)
//     + ((key>>4)&1)*4 + (key&3)
__global__ __launch_bounds__(512, 2) void proj_gemm(
    const u16* __restrict__ qc, const u16* __restrict__ kc, const u16* __restrict__ vc,
    const u16* __restrict__ Wq, const u16* __restrict__ Wk, const u16* __restrict__ Wv,
    const float* __restrict__ bq, const float* __restrict__ bk, const float* __restrict__ bv,
    u16* __restrict__ Qb, u16* __restrict__ Kb, u16* __restrict__ Vtb) {
  __shared__ __align__(16) u16 As[2 * 2 * 8192];
  __shared__ __align__(16) u16 Bs[2 * 2 * 8192];
  const int z = blockIdx.z;
  const u16* A = (z == 0) ? qc : (z == 1) ? kc : vc;
  const u16* W = (z == 0) ? Wq : (z == 1) ? Wk : Wv;
  const float* bias = (z == 0) ? bq : (z == 1) ? bk : bv;
  const int m0 = blockIdx.x * 256, n0 = blockIdx.y * 256;

  floatx4 acc[8][4] = {};
  gemm256_core(A + (size_t)m0 * KK, W + (size_t)n0 * KK, As, Bs, acc);

  const int tid = threadIdx.x;
  const int w = tid >> 6, lane = tid & 63;
  const int lr = lane & 15, lq = lane >> 4;
  const int wm = w >> 2, wn = w & 3;
  const int row0 = m0 + wm * 128;
  const int col0 = n0 + wn * 64;

  if (z == 2) {
    // V tiled store: rr=0..3 are consecutive keys -> still one packed uint2
#pragma unroll
    for (int fc = 0; fc < 4; ++fc) {
      const int col = col0 + fc * 16 + lr;
      const float bv_ = bias[col];
      const int h = col >> 6, dk = col & 63;
#pragma unroll
      for (int fr = 0; fr < 8; ++fr) {
        const int row = row0 + fr * 16 + lq * 4;
        const int b = row >> 11, s = row & (SS - 1);
        const int kt = s >> 6, key = s & 63;  // key&3 == 0 (row is 4-aligned)
        uint2 pk;
        pk.x = pack2bf(acc[fr][fc][0] + bv_, acc[fr][fc][1] + bv_);
        pk.y = pack2bf(acc[fr][fc][2] + bv_, acc[fr][fc][3] + bv_);
        const size_t addr = (((size_t)(b * HH + h)) * 32 + kt) * 4096 +
                            1024 * (dk >> 4) + 512 * (key >> 5) +
                            128 * ((key >> 2) & 3) + 8 * (dk & 15) +
                            ((key >> 4) & 1) * 4;
        *(uint2*)&Vtb[addr] = pk;
      }
    }
  } else {
    u16* out = (z == 0) ? Qb : Kb;
    const float sc = (z == 0) ? QSCALE : 1.0f;
#pragma unroll
    for (int fc = 0; fc < 4; ++fc) {
      const int col = col0 + fc * 16 + lr;
      const float bv_ = bias[col];
#pragma unroll
      for (int fr = 0; fr < 8; ++fr)
#pragma unroll
        for (int rr = 0; rr < 4; ++rr) {
          const int row = row0 + fr * 16 + lq * 4 + rr;
          out[(size_t)row * NN + col] = f2bf((acc[fr][fc][rr] + bv_) * sc);
        }
    }
  }
}

// ---------------- output GEMM (fp32 store) ----------------
__global__ __launch_bounds__(512, 2) void out_gemm(const u16* __restrict__ A,
                                                   const u16* __restrict__ W,
                                                   const float* __restrict__ bias,
                                                   float* __restrict__ out) {
  __shared__ __align__(16) u16 As[2 * 2 * 8192];
  __shared__ __align__(16) u16 Bs[2 * 2 * 8192];
  const int m0 = blockIdx.x * 256, n0 = blockIdx.y * 256;
  floatx4 acc[8][4] = {};
  gemm256_core(A + (size_t)m0 * KK, W + (size_t)n0 * KK, As, Bs, acc);

  const int tid = threadIdx.x;
  const int w = tid >> 6, lane = tid & 63;
  const int lr = lane & 15, lq = lane >> 4;
  const int wm = w >> 2, wn = w & 3;
  const int row0 = m0 + wm * 128;
  const int col0 = n0 + wn * 64;
#pragma unroll
  for (int fc = 0; fc < 4; ++fc) {
    const int col = col0 + fc * 16 + lr;
    const float bv = bias[col];
#pragma unroll
    for (int fr = 0; fr < 8; ++fr)
#pragma unroll
      for (int rr = 0; rr < 4; ++rr) {
        const int row = row0 + fr * 16 + lq * 4 + rr;
        out[(size_t)row * NN + col] = acc[fr][fc][rr] + bv;
      }
  }
}

// ---------------- flash attention r10: 8 waves x 16 q-rows, MFMA denominator ----------------
// r9 post-mortem: in-wave QK/PV/exp pipelining was NEUTRAL -- the kernel is
// latency-bound with only 16 waves/CU (4096 waves fixed by 32-rows/wave), and
// VALUBusy*dur ~44us is the largest pipe consumer (exp + denom adds + pack).
// r10: (1) halve per-wave work to ONE 16-row strip, 8 waves per 512-thread
// block -> 8192 waves, 32/CU (TLP x2). Same r8-verified per-strip math.
// (2) denominator via 2 extra MFMAs against a ones B-frag per iter:
//     acc_l = mfma(pa[0],ones) + mfma(pa[1],ones) -> D[q][*] row-sum,
//     replicated over cols, accumulated across iters in C. Kills 32 VALU
//     adds/iter AND the end-of-kernel shuffle redistribute (acc_l rows are
//     already the o rows q=4lq+r).
// Staging: wave w stages K-chunk w (key 16*(w>>1)+lr, dk 32*(w&1)+8lq+j) and
// V-chunk w (tiled image, linear). 2 loads/wave/iter; ledger: outstanding <=
// [K(kt),V(kt),K(kt+1),V(kt+1)] -> vmcnt(2) lands K(kt),V(kt). 2 barriers/iter.
// LDS 2x8K + 2x8K = 32768 -> 4 blocks/CU x 8 waves = 32 waves/CU.
// VGPR budget: one strip ~58 regs; __launch_bounds__(512,8) caps at 64
// (spill tripwire: WRITE_SIZE must stay 16.4 MB).
__global__ __launch_bounds__(512, 8) void attn_kernel(const u16* __restrict__ Q,
                                                      const u16* __restrict__ Kmat,
                                                      const u16* __restrict__ Vt,
                                                      u16* __restrict__ ctx) {
  __shared__ __align__(16) u16 Ks[2][4096];  // chunk 2t+half: key 16t+lr, dk 32*half+8lq+j
  __shared__ __align__(16) u16 Vs[2][4096];  // tiled image: chunk 2t+H, lane*8
  const int tid = threadIdx.x;
  const int w = tid >> 6, lane = tid & 63;
  const int lr = lane & 15, lq = lane >> 4;
  const int bh = blockIdx.x, b = bh >> 4, h = bh & 15;
  const int q0 = blockIdx.y * 128;

  // Q fragment (B-operand layout: n=q=lr, k-slot (lq,j) -> dk=8lq+j (+32))
  short8v qf[2];
  {
    const u16* qp = Q + ((size_t)(b * SS + q0 + w * 16 + lr)) * DD + h * 64 + lq * 8;
    qf[0] = *(const short8v*)qp;
    qf[1] = *(const short8v*)(qp + 32);
  }
  // ones B-frag (bf16 1.0 in every slot) for the denominator MFMA
  short8v ones;
  {
    union { u16 u[8]; short8v v; } ob;
#pragma unroll
    for (int i = 0; i < 8; ++i) ob.u[i] = 0x3F80;
    ones = ob.v;
  }
  floatx4 o[4] = {};      // o[t]: row q=4lq+r, col dk=16t+lr
  floatx4 acc_l = {};     // denom: row q=4lq+r (col-replicated)

  // wave w stages K-chunk w and V-chunk w each iter (1 global_load_lds each)
  const u16* kp = Kmat + ((size_t)(b * SS + (w >> 1) * 16 + lr)) * DD + h * 64 +
                  (w & 1) * 32 + lq * 8;
  const u16* vp = Vt + ((size_t)(b * HH + h)) * (32 * 4096) + w * 512 + lane * 8;

  // prologue: stage K(0),V(0) -> buf 0
  load_lds16(kp, &Ks[0][w * 512]);
  load_lds16(vp, &Vs[0][w * 512]);
  kp += 64 * DD; vp += 4096;

#pragma unroll 1
  for (int kt = 0; kt < SS / 64; ++kt) {
    const int bf = kt & 1;
    const bool haveNext = (kt + 1 < SS / 64);
    __builtin_amdgcn_s_barrier();  // B0: closes QK/PV(kt-1) reads of buf bf^1
    if (haveNext) {
      load_lds16(kp, &Ks[bf ^ 1][w * 512]);
      load_lds16(vp, &Vs[bf ^ 1][w * 512]);
      kp += 64 * DD; vp += 4096;
      // outstanding <= [K(kt),V(kt),K(kt+1),V(kt+1)] -> vmcnt(2) lands K,V(kt)
      asm volatile("s_waitcnt vmcnt(2)" ::: "memory");
    } else {
      asm volatile("s_waitcnt vmcnt(0)" ::: "memory");
    }
    __builtin_amdgcn_s_barrier();  // B1: K(kt),V(kt) visible to all waves

    // swapped QK: sc[t] = S[key=16t+4lq+r][q=lr] (A=K, B=Q)
    floatx4 sc[4] = {};
    __builtin_amdgcn_s_setprio(1);
#pragma unroll
    for (int t = 0; t < 4; ++t) {
      short8v kb0 = *(const short8v*)&Ks[bf][t * 1024 + lane * 8];
      short8v kb1 = *(const short8v*)&Ks[bf][t * 1024 + 512 + lane * 8];
      sc[t] = mfma_k32(kb0, qf[0], sc[t]);
      sc[t] = mfma_k32(kb1, qf[1], sc[t]);
    }
    __builtin_amdgcn_s_setprio(0);

    // softmax exp + lane-local P pack: pa[H] slot j = sc[2H+(j>>2)][j&3]
    short8v pa[2];
#pragma unroll
    for (int t = 0; t < 4; ++t)
#pragma unroll
      for (int r = 0; r < 4; ++r)
        sc[t][r] = __builtin_amdgcn_exp2f(sc[t][r]);
#pragma unroll
    for (int H = 0; H < 2; ++H) {
      union { u32 u[4]; short8v v; } pb;
      pb.u[0] = pack2bf(sc[2 * H][0], sc[2 * H][1]);
      pb.u[1] = pack2bf(sc[2 * H][2], sc[2 * H][3]);
      pb.u[2] = pack2bf(sc[2 * H + 1][0], sc[2 * H + 1][1]);
      pb.u[3] = pack2bf(sc[2 * H + 1][2], sc[2 * H + 1][3]);
      pa[H] = pb.v;
    }

    // PV + denominator, all in the matrix pipe
    const u16* vsb = &Vs[bf][0];
    __builtin_amdgcn_s_setprio(1);
#pragma unroll
    for (int t = 0; t < 4; ++t) {
      short8v vb0 = *(const short8v*)&vsb[(2 * t) * 512 + lane * 8];
      short8v vb1 = *(const short8v*)&vsb[(2 * t + 1) * 512 + lane * 8];
      o[t] = mfma_k32(pa[0], vb0, o[t]);
      o[t] = mfma_k32(pa[1], vb1, o[t]);
    }
    acc_l = mfma_k32(pa[0], ones, acc_l);
    acc_l = mfma_k32(pa[1], ones, acc_l);
    __builtin_amdgcn_s_setprio(0);
  }

  // denom already in the o-row layout (q=4lq+r, col-replicated)
#pragma unroll
  for (int r = 0; r < 4; ++r) {
    const int sq = q0 + w * 16 + lq * 4 + r;
    u16* cp = ctx + ((size_t)(b * SS + sq)) * DD + h * 64;
    const float iv = 1.0f / acc_l[r];
#pragma unroll
    for (int t = 0; t < 4; ++t)
      cp[t * 16 + lr] = f2bf(o[t][r] * iv);
  }
}

// ---------------- launch ----------------
extern "C" void kernel_launch(void* const* d_in, const int* in_sizes, int n_in,
                              void* d_out, int out_size, void* d_ws, size_t ws_size,
                              hipStream_t stream) {
  const float* query = (const float*)d_in[0];
  const float* key   = (const float*)d_in[1];
  const float* value = (const float*)d_in[2];
  const float* Wq = (const float*)d_in[3];  const float* bq = (const float*)d_in[4];
  const float* Wk = (const float*)d_in[5];  const float* bk = (const float*)d_in[6];
  const float* Wv = (const float*)d_in[7];  const float* bv = (const float*)d_in[8];
  const float* Wo = (const float*)d_in[9];  const float* bo = (const float*)d_in[10];
  float* out = (float*)d_out;

  char* ws = (char*)d_ws;
  size_t off = 0;
  u16* Wb   = (u16*)(ws + off); off += (size_t)4 * DD * DD * 2;  // Wq,Wk,Wv,Wo bf16
  u16* Qb   = (u16*)(ws + off); off += (size_t)MM * DD * 2;      // scaled Q [B,S,D]
  u16* Kb   = (u16*)(ws + off); off += (size_t)MM * DD * 2;      // [B,S,D]
  u16* Vtb  = (u16*)(ws + off); off += (size_t)MM * DD * 2;      // tiled V (see proj_gemm)
  u16* qc   = (u16*)(ws + off);
  u16* ctxb = qc;               off += (size_t)MM * DD * 2;      // ctx aliases qc
  u16* kc = (u16*)d_out;                       // scratch in d_out (overwritten last)
  u16* vc = (u16*)d_out + (size_t)MM * DD;
  u16* Wq_b = Wb, *Wk_b = Wb + (size_t)DD * DD, *Wv_b = Wb + (size_t)2 * DD * DD,
     *Wo_b = Wb + (size_t)3 * DD * DD;

  const int wn = DD * DD, an = MM * DD;
  cvt_w4<<<dim3(wn / 2048, 4), 256, 0, stream>>>(Wq, Wk, Wv, Wo, Wb);
  cvt_a3<<<dim3(an / 2048, 3), 256, 0, stream>>>(query, key, value, qc, kc, vc);

  proj_gemm<<<dim3(MM / 256, NN / 256, 3), 512, 0, stream>>>(
      qc, kc, vc, Wq_b, Wk_b, Wv_b, bq, bk, bv, Qb, Kb, Vtb);

  attn_kernel<<<dim3(BB * HH, SS / 128), 512, 0, stream>>>(Qb, Kb, Vtb, ctxb);

  out_gemm<<<dim3(MM / 256, NN / 256), 512, 0, stream>>>(ctxb, Wo_b, bo, out);
}